// Round 3
// baseline (4517.295 us; speedup 1.0000x reference)
//
#include <hip/hip_runtime.h>
#include <math.h>

#define FM 32
#define N_EDGES 3200000
#define VAR_COUNT 100000
#define CONST_COUNT 50000
#define LN_EPS 1e-5f

#define EPB 4096                                // edges per sort block
#define ABLK ((N_EDGES + EPB - 1) / EPB)        // 782
#define NBUCK_C ((CONST_COUNT + 63) >> 6)       // 782 buckets of 64 dests
#define NBUCK_V ((VAR_COUNT + 127) >> 7)        // 782 buckets of 128 dests

static __device__ __forceinline__ float warp_sum32(float v) {
#pragma unroll
    for (int m = 16; m; m >>= 1) v += __shfl_xor(v, m);
    return v;
}

__global__ void fill_ones(float* __restrict__ p, int n) {
    int i = blockIdx.x * 256 + threadIdx.x;
    if (i < n) p[i] = 1.0f;
}

// ---------------- block-local bucket sort (no global atomics) ----------------
// Each block owns edges [blk*EPB, blk*EPB+nb) and region recs[blk*EPB ...].
// Records are grouped by bucket (dest >> DSHIFT) inside the region; the
// per-bucket offsets go to lscan[blk][0..NBUCK] (entry NBUCK = nb).

template <int DSHIFT, int NBUCK>
__global__ __launch_bounds__(256) void bucket_sort(
    const int* __restrict__ dest_arr, const int* __restrict__ src_arr,
    const float* __restrict__ val_arr,
    int2* __restrict__ recs, int* __restrict__ lscan, int n) {
    constexpr int LSTRIDE = NBUCK + 2;
    __shared__ int hist[NBUCK];
    __shared__ int cursor[NBUCK];
    __shared__ int chunk[256];
    __shared__ int2 stage[EPB];
    const int t = threadIdx.x;
    const int base = blockIdx.x * EPB;
    const int nb = min(EPB, n - base);
    for (int i = t; i < NBUCK; i += 256) hist[i] = 0;
    __syncthreads();
    int dg[16], pk[16], vb[16];
#pragma unroll
    for (int k = 0; k < 16; ++k) {
        int j = k * 256 + t;
        dg[k] = -1;
        if (j < nb) {
            int dest = dest_arr[base + j];
            int src  = src_arr[base + j];
            vb[k] = __float_as_int(val_arr[base + j]);
            dg[k] = dest >> DSHIFT;
            pk[k] = ((dest & ((1 << DSHIFT) - 1)) << 20) | src;
            atomicAdd(&hist[dg[k]], 1);
        }
    }
    __syncthreads();
    // exclusive scan of hist (4 bins per thread + 256-wide Hillis-Steele)
    int sum = 0;
#pragma unroll
    for (int k = 0; k < 4; ++k) {
        int idx = t * 4 + k;
        if (idx < NBUCK) sum += hist[idx];
    }
    chunk[t] = sum;
    __syncthreads();
    for (int off = 1; off < 256; off <<= 1) {
        int v = (t >= off) ? chunk[t - off] : 0;
        __syncthreads();
        chunk[t] += v;
        __syncthreads();
    }
    int run = chunk[t] - sum;
#pragma unroll
    for (int k = 0; k < 4; ++k) {
        int idx = t * 4 + k;
        if (idx < NBUCK) {
            int h = hist[idx];
            hist[idx] = run;     // exclusive offset
            cursor[idx] = run;
            run += h;
        }
    }
    __syncthreads();
    {
        int* lp = lscan + (size_t)blockIdx.x * LSTRIDE;
        for (int i = t; i < NBUCK; i += 256) lp[i] = hist[i];
        if (t == 0) lp[NBUCK] = nb;
    }
    // rank (LDS atomic) + stage sorted in LDS
#pragma unroll
    for (int k = 0; k < 16; ++k) {
        if (dg[k] >= 0) {
            int pos = atomicAdd(&cursor[dg[k]], 1);
            stage[pos] = make_int2(pk[k], vb[k]);
        }
    }
    __syncthreads();
    for (int j = t; j < nb; j += 256) recs[(size_t)base + j] = stage[j];
}

// ---------------- per-bucket gather with LDS fp32 accumulators ----------------
// One block per bucket (DL destination rows). Walks the 782 per-sort-block
// runs of its bucket; all reads are cacheable; one coalesced write per row.

template <int DSHIFT, int DL, int NBUCK>
__global__ __launch_bounds__(256) void bucket_gather(
    const int* __restrict__ lscan, const int2* __restrict__ recs,
    const float* __restrict__ src, float* __restrict__ dst, int nrows) {
    constexpr int LSTRIDE = NBUCK + 2;
    __shared__ float acc[DL][33];
    const int t = threadIdx.x, g = t >> 5, f = t & 31;
    float* accf = &acc[0][0];
    for (int i = t; i < DL * 33; i += 256) accf[i] = 0.0f;
    __syncthreads();
    const int d = blockIdx.x;
    for (int b = g; b < ABLK; b += 8) {
        const int* lp = lscan + (size_t)b * LSTRIDE + d;
        int j0 = lp[0], j1 = lp[1];
        const int2* rp = recs + (size_t)b * EPB;
        int j = j0;
        for (; j + 2 <= j1; j += 2) {
            int2 ra = rp[j], rb = rp[j + 1];
            float xa = src[(size_t)(ra.x & 0xFFFFF) * FM + f];
            float xb = src[(size_t)(rb.x & 0xFFFFF) * FM + f];
            atomicAdd(&acc[ra.x >> 20][f], xa * __int_as_float(ra.y));
            atomicAdd(&acc[rb.x >> 20][f], xb * __int_as_float(rb.y));
        }
        if (j < j1) {
            int2 ra = rp[j];
            atomicAdd(&acc[ra.x >> 20][f],
                      src[(size_t)(ra.x & 0xFFFFF) * FM + f] * __int_as_float(ra.y));
        }
    }
    __syncthreads();
    const int d0 = d << DSHIFT;
    for (int r = g; r < DL; r += 8) {
        int row = d0 + r;
        if (row < nrows) dst[(size_t)row * FM + f] = acc[r][f];
    }
}

// ---------------- fallback atomic scatter (used only if ws too small) ----------------

__global__ __launch_bounds__(256) void scatter_edges(
    const int* __restrict__ src_idx, const int* __restrict__ dst_idx,
    const float* __restrict__ ev, const float* __restrict__ src,
    float* __restrict__ dst, int n_edges) {
    int e = blockIdx.x * 8 + (threadIdx.x >> 5);
    int f = threadIdx.x & 31;
    if (e >= n_edges) return;
    atomicAdd(&dst[(size_t)dst_idx[e] * FM + f], src[(size_t)src_idx[e] * FM + f] * ev[e]);
}

// ---------------- MLP + LayerNorm kernels ----------------

// scalar -> 64 (relu) -> 32, LN. Writes to two destinations (emb and cons).
__global__ __launch_bounds__(256) void pc_mlp(
    const float* __restrict__ cond,
    const float* __restrict__ W1, const float* __restrict__ b1,
    const float* __restrict__ W2, const float* __restrict__ b2,
    float* __restrict__ dst, float* __restrict__ dst2, int nrows) {
    __shared__ float sW2[64 * FM];
    __shared__ float sh[4][64];
    for (int i = threadIdx.x; i < 64 * FM; i += 256) sW2[i] = W2[i];
    int g = threadIdx.x >> 6, l = threadIdx.x & 63, l32 = l & 31, half = l >> 5;
    float w1l = W1[l], b1l = b1[l], b2l = b2[l32];
    __syncthreads();
    for (int row = blockIdx.x * 4 + g; row < nrows; row += gridDim.x * 4) {
        float c = cond[row];
        sh[g][l] = fmaxf(fmaf(c, w1l, b1l), 0.0f);
        float y = 0.0f;
#pragma unroll
        for (int k = 0; k < 32; k += 4) {
            float4 hv = *(const float4*)&sh[g][half * 32 + k];
            y = fmaf(hv.x, sW2[(half * 32 + k + 0) * FM + l32], y);
            y = fmaf(hv.y, sW2[(half * 32 + k + 1) * FM + l32], y);
            y = fmaf(hv.z, sW2[(half * 32 + k + 2) * FM + l32], y);
            y = fmaf(hv.w, sW2[(half * 32 + k + 3) * FM + l32], y);
        }
        y += __shfl_xor(y, 32);
        y += b2l;
        float s = warp_sum32(y);
        float mu = s * (1.0f / 32.0f);
        float d = y - mu;
        float v = warp_sum32(d * d);
        if (half == 0) {
            float o = d * rsqrtf(v * (1.0f / 32.0f) + LN_EPS);
            dst[(size_t)row * FM + l32] = o;
            dst2[(size_t)row * FM + l32] = o;
        }
    }
}

// IN = NSEG*32 -> 64 (relu) -> 32, LN. In-place safe per row.
template <int NSEG>
__global__ __launch_bounds__(256) void mlp_ln(
    const float* __restrict__ s0, const float* __restrict__ s1,
    const float* __restrict__ s2,
    const float* __restrict__ W1, const float* __restrict__ b1,
    const float* __restrict__ W2, const float* __restrict__ b2,
    float* __restrict__ dst, int nrows) {
    constexpr int IN = NSEG * FM;
    __shared__ float sW1[IN * 64];
    __shared__ float sW2[64 * FM];
    __shared__ float sx[4][IN];
    __shared__ float sh[4][64];
    for (int i = threadIdx.x; i < IN * 64; i += 256) sW1[i] = W1[i];
    for (int i = threadIdx.x; i < 64 * FM; i += 256) sW2[i] = W2[i];
    int g = threadIdx.x >> 6, l = threadIdx.x & 63, l32 = l & 31, half = l >> 5;
    float b1l = b1[l], b2l = b2[l32];
    __syncthreads();
    for (int row = blockIdx.x * 4 + g; row < nrows; row += gridDim.x * 4) {
#pragma unroll
        for (int i = l; i < IN; i += 64) {
            const float* s = (i < 32) ? s0 : (i < 64) ? s1 : s2;
            sx[g][i] = s[(size_t)row * FM + (i & 31)];
        }
        float acc = b1l;
#pragma unroll
        for (int k = 0; k < IN; k += 4) {
            float4 xv = *(const float4*)&sx[g][k];
            acc = fmaf(xv.x, sW1[(k + 0) * 64 + l], acc);
            acc = fmaf(xv.y, sW1[(k + 1) * 64 + l], acc);
            acc = fmaf(xv.z, sW1[(k + 2) * 64 + l], acc);
            acc = fmaf(xv.w, sW1[(k + 3) * 64 + l], acc);
        }
        sh[g][l] = fmaxf(acc, 0.0f);
        float y = 0.0f;
#pragma unroll
        for (int k = 0; k < 32; k += 4) {
            float4 hv = *(const float4*)&sh[g][half * 32 + k];
            y = fmaf(hv.x, sW2[(half * 32 + k + 0) * FM + l32], y);
            y = fmaf(hv.y, sW2[(half * 32 + k + 1) * FM + l32], y);
            y = fmaf(hv.z, sW2[(half * 32 + k + 2) * FM + l32], y);
            y = fmaf(hv.w, sW2[(half * 32 + k + 3) * FM + l32], y);
        }
        y += __shfl_xor(y, 32);
        y += b2l;
        float s = warp_sum32(y);
        float mu = s * (1.0f / 32.0f);
        float d = y - mu;
        float v = warp_sum32(d * d);
        if (half == 0) dst[(size_t)row * FM + l32] = d * rsqrtf(v * (1.0f / 32.0f) + LN_EPS);
    }
}

// 32 -> 64 (relu) -> 16, sigmoid.
__global__ __launch_bounds__(256) void out_mlp(
    const float* __restrict__ x,
    const float* __restrict__ W1, const float* __restrict__ b1,
    const float* __restrict__ W2, const float* __restrict__ b2,
    float* __restrict__ dst, int nrows) {
    __shared__ float sW1[FM * 64];
    __shared__ float sW2[64 * 16];
    __shared__ float sx[4][FM];
    __shared__ float sh[4][64];
    for (int i = threadIdx.x; i < FM * 64; i += 256) sW1[i] = W1[i];
    for (int i = threadIdx.x; i < 64 * 16; i += 256) sW2[i] = W2[i];
    int g = threadIdx.x >> 6, l = threadIdx.x & 63;
    int o = l & 15, q = l >> 4;
    float b1l = b1[l];
    float b2o = b2[o];
    __syncthreads();
    for (int row = blockIdx.x * 4 + g; row < nrows; row += gridDim.x * 4) {
        if (l < FM) sx[g][l] = x[(size_t)row * FM + l];
        float acc = b1l;
#pragma unroll
        for (int k = 0; k < FM; k += 4) {
            float4 xv = *(const float4*)&sx[g][k];
            acc = fmaf(xv.x, sW1[(k + 0) * 64 + l], acc);
            acc = fmaf(xv.y, sW1[(k + 1) * 64 + l], acc);
            acc = fmaf(xv.z, sW1[(k + 2) * 64 + l], acc);
            acc = fmaf(xv.w, sW1[(k + 3) * 64 + l], acc);
        }
        sh[g][l] = fmaxf(acc, 0.0f);
        float y = 0.0f;
#pragma unroll
        for (int k = 0; k < 16; k += 4) {
            int kk = q * 16 + k;
            float4 hv = *(const float4*)&sh[g][kk];
            y = fmaf(hv.x, sW2[(kk + 0) * 16 + o], y);
            y = fmaf(hv.y, sW2[(kk + 1) * 16 + o], y);
            y = fmaf(hv.z, sW2[(kk + 2) * 16 + o], y);
            y = fmaf(hv.w, sW2[(kk + 3) * 16 + o], y);
        }
        y += __shfl_xor(y, 16);
        y += __shfl_xor(y, 32);
        if (q == 0) dst[(size_t)row * 16 + o] = 1.0f / (1.0f + expf(-(y + b2o)));
    }
}

// ---------------- launcher ----------------

extern "C" void kernel_launch(void* const* d_in, const int* in_sizes, int n_in,
                              void* d_out, int out_size, void* d_ws, size_t ws_size,
                              hipStream_t stream) {
    const int*   edge_var   = (const int*)d_in[0];
    const int*   edge_const = (const int*)d_in[1];
    const float* edge_val   = (const float*)d_in[2];
    const float* cond       = (const float*)d_in[3];
    const float* pc_W1 = (const float*)d_in[6];
    const float* pc_b1 = (const float*)d_in[7];
    const float* pc_W2 = (const float*)d_in[8];
    const float* pc_b2 = (const float*)d_in[9];
    const float* cu_W1 = (const float*)d_in[10];
    const float* cu_b1 = (const float*)d_in[11];
    const float* cu_W2 = (const float*)d_in[12];
    const float* cu_b2 = (const float*)d_in[13];
    const float* vu_W1 = (const float*)d_in[14];
    const float* vu_b1 = (const float*)d_in[15];
    const float* vu_W2 = (const float*)d_in[16];
    const float* vu_b2 = (const float*)d_in[17];
    const float* out_W1 = (const float*)d_in[18];
    const float* out_b1 = (const float*)d_in[19];
    const float* out_W2 = (const float*)d_in[20];
    const float* out_b2 = (const float*)d_in[21];

    float* ws = (float*)d_ws;
    size_t off = 0;
    auto alloc = [&](size_t nelems) {
        float* p = ws + off;
        off += (nelems + 15) & ~(size_t)15;
        return p;
    };
    float* emb     = alloc(CONST_COUNT * FM);
    float* cons    = alloc(CONST_COUNT * FM);
    float* vars    = alloc(VAR_COUNT * FM);
    float* msg     = alloc(VAR_COUNT * FM);
    int2*  recs_c  = (int2*)alloc((size_t)N_EDGES * 2);
    int2*  recs_v  = (int2*)alloc((size_t)N_EDGES * 2);
    int*   lscan_c = (int*)alloc((size_t)ABLK * (NBUCK_C + 2));
    int*   lscan_v = (int*)alloc((size_t)ABLK * (NBUCK_V + 2));
    size_t need_bytes = off * sizeof(float);
    bool fast = ws_size >= need_bytes;

    if (fast) {
        // v2c direction: dest = edge_const, payload src = edge_var
        bucket_sort<6, NBUCK_C><<<ABLK, 256, 0, stream>>>(
            edge_const, edge_var, edge_val, recs_c, lscan_c, N_EDGES);
        // c2v direction: dest = edge_var, payload src = edge_const
        bucket_sort<7, NBUCK_V><<<ABLK, 256, 0, stream>>>(
            edge_var, edge_const, edge_val, recs_v, lscan_v, N_EDGES);
    }

    fill_ones<<<(VAR_COUNT * FM + 255) / 256, 256, 0, stream>>>(vars, VAR_COUNT * FM);
    pc_mlp<<<1024, 256, 0, stream>>>(cond, pc_W1, pc_b1, pc_W2, pc_b2, emb, cons,
                                     CONST_COUNT);

    for (int pass = 0; pass < 3; ++pass) {
        if (fast) {
            bucket_gather<6, 64, NBUCK_C><<<NBUCK_C, 256, 0, stream>>>(
                lscan_c, recs_c, vars, msg, CONST_COUNT);
        } else {
            hipMemsetAsync(msg, 0, (size_t)CONST_COUNT * FM * sizeof(float), stream);
            scatter_edges<<<N_EDGES / 8, 256, 0, stream>>>(edge_var, edge_const, edge_val,
                                                           vars, msg, N_EDGES);
        }
        mlp_ln<3><<<1024, 256, 0, stream>>>(cons, emb, msg, cu_W1, cu_b1, cu_W2, cu_b2,
                                            cons, CONST_COUNT);
        if (fast) {
            bucket_gather<7, 128, NBUCK_V><<<NBUCK_V, 256, 0, stream>>>(
                lscan_v, recs_v, cons, msg, VAR_COUNT);
        } else {
            hipMemsetAsync(msg, 0, (size_t)VAR_COUNT * FM * sizeof(float), stream);
            scatter_edges<<<N_EDGES / 8, 256, 0, stream>>>(edge_const, edge_var, edge_val,
                                                           cons, msg, N_EDGES);
        }
        mlp_ln<2><<<1024, 256, 0, stream>>>(vars, msg, nullptr, vu_W1, vu_b1, vu_W2, vu_b2,
                                            vars, VAR_COUNT);
    }

    out_mlp<<<1024, 256, 0, stream>>>(vars, out_W1, out_b1, out_W2, out_b2,
                                      (float*)d_out, VAR_COUNT);
}

// Round 4
// 4444.203 us; speedup vs baseline: 1.0164x; 1.0164x over previous
//
#include <hip/hip_runtime.h>
#include <hip/hip_fp16.h>
#include <math.h>

#define FM 32
#define N_EDGES 3200000
#define VAR_COUNT 100000
#define CONST_COUNT 50000
#define LN_EPS 1e-5f

#define EPB 4096                 // edges per sort block
#define ABLK 782                 // ceil(N_EDGES / EPB)
#define NB 782                   // buckets (64 consts or 128 vars each)
#define AB2 784                  // padded stride for transposed matrices
#define LSTRIDE 784              // NB + 2

static __device__ __forceinline__ float warp_sum32(float v) {
#pragma unroll
    for (int m = 16; m; m >>= 1) v += __shfl_xor(v, m);
    return v;
}

__global__ void init_vars(float* __restrict__ v, __half* __restrict__ v16, int n) {
    int i = blockIdx.x * 256 + threadIdx.x;
    if (i < n) { v[i] = 1.0f; if (v16) v16[i] = __float2half(1.0f); }
}

// ---------------- block-local bucket sort (no global atomics) ----------------
// Block owns edges [blk*EPB, blk*EPB+nb); writes records grouped by bucket
// (dest >> DSHIFT) to recs_tmp[blk*EPB...], per-block bucket offsets to lscan,
// and run lengths transposed to rlen_T[bucket][blk].

template <int DSHIFT>
__global__ __launch_bounds__(256) void bucket_sort(
    const int* __restrict__ dest_arr, const int* __restrict__ src_arr,
    const float* __restrict__ val_arr,
    int2* __restrict__ recs_tmp, int* __restrict__ lscan, int* __restrict__ rlen_T,
    int n) {
    __shared__ int hist[NB];
    __shared__ int cursor[NB];
    __shared__ int chunk[256];
    __shared__ int2 stage[EPB];
    const int t = threadIdx.x;
    const int base = blockIdx.x * EPB;
    const int nb = min(EPB, n - base);
    for (int i = t; i < NB; i += 256) hist[i] = 0;
    __syncthreads();
    int dg[16], pk[16], vb[16];
#pragma unroll
    for (int k = 0; k < 16; ++k) {
        int j = k * 256 + t;
        dg[k] = -1;
        if (j < nb) {
            int dest = dest_arr[base + j];
            int src  = src_arr[base + j];
            vb[k] = __float_as_int(val_arr[base + j]);
            dg[k] = dest >> DSHIFT;
            pk[k] = ((dest & ((1 << DSHIFT) - 1)) << 20) | src;
            atomicAdd(&hist[dg[k]], 1);
        }
    }
    __syncthreads();
    // exclusive scan of hist (4 consecutive bins/thread + block scan)
    int sum = 0;
#pragma unroll
    for (int k = 0; k < 4; ++k) {
        int idx = t * 4 + k;
        if (idx < NB) sum += hist[idx];
    }
    chunk[t] = sum;
    __syncthreads();
    for (int off = 1; off < 256; off <<= 1) {
        int v = (t >= off) ? chunk[t - off] : 0;
        __syncthreads();
        chunk[t] += v;
        __syncthreads();
    }
    int run = chunk[t] - sum;
#pragma unroll
    for (int k = 0; k < 4; ++k) {
        int idx = t * 4 + k;
        if (idx < NB) {
            int h = hist[idx];
            rlen_T[(size_t)idx * AB2 + blockIdx.x] = h;
            hist[idx] = run;
            cursor[idx] = run;
            run += h;
        }
    }
    __syncthreads();
    {
        int* lp = lscan + (size_t)blockIdx.x * LSTRIDE;
        for (int i = t; i < NB; i += 256) lp[i] = hist[i];
        if (t == 0) lp[NB] = nb;
    }
#pragma unroll
    for (int k = 0; k < 16; ++k) {
        if (dg[k] >= 0) {
            int pos = atomicAdd(&cursor[dg[k]], 1);
            stage[pos] = make_int2(pk[k], vb[k]);
        }
    }
    __syncthreads();
    for (int j = t; j < nb; j += 256) recs_tmp[(size_t)base + j] = stage[j];
}

// Per-bucket exclusive scan over blocks: goff_T[k][b], bucket totals btot[k].
__global__ __launch_bounds__(256) void scan_cols(
    const int* __restrict__ rlen_T, int* __restrict__ goff_T, int* __restrict__ btot) {
    __shared__ int ls[256];
    const int t = threadIdx.x;
    const int* rp = rlen_T + (size_t)blockIdx.x * AB2;
    int* gp = goff_T + (size_t)blockIdx.x * AB2;
    int idx = t * 4;
    int a0 = (idx + 0 < ABLK) ? rp[idx + 0] : 0;
    int a1 = (idx + 1 < ABLK) ? rp[idx + 1] : 0;
    int a2 = (idx + 2 < ABLK) ? rp[idx + 2] : 0;
    int a3 = (idx + 3 < ABLK) ? rp[idx + 3] : 0;
    int tsum = a0 + a1 + a2 + a3;
    ls[t] = tsum;
    __syncthreads();
    for (int off = 1; off < 256; off <<= 1) {
        int v = (t >= off) ? ls[t - off] : 0;
        __syncthreads();
        ls[t] += v;
        __syncthreads();
    }
    int excl = ls[t] - tsum;
    if (idx + 0 < ABLK) gp[idx + 0] = excl;
    if (idx + 1 < ABLK) gp[idx + 1] = excl + a0;
    if (idx + 2 < ABLK) gp[idx + 2] = excl + a0 + a1;
    if (idx + 3 < ABLK) gp[idx + 3] = excl + a0 + a1 + a2;
    if (t == 255) btot[blockIdx.x] = ls[255];
}

// Exclusive scan of bucket totals -> bucket base offsets bb[0..NB], bb[NB]=total.
__global__ __launch_bounds__(256) void scan_btot(
    const int* __restrict__ btot, int* __restrict__ bb, int n, int total) {
    __shared__ int ls[256];
    const int t = threadIdx.x;
    int idx = t * 4;
    int a0 = (idx + 0 < n) ? btot[idx + 0] : 0;
    int a1 = (idx + 1 < n) ? btot[idx + 1] : 0;
    int a2 = (idx + 2 < n) ? btot[idx + 2] : 0;
    int a3 = (idx + 3 < n) ? btot[idx + 3] : 0;
    int tsum = a0 + a1 + a2 + a3;
    ls[t] = tsum;
    __syncthreads();
    for (int off = 1; off < 256; off <<= 1) {
        int v = (t >= off) ? ls[t - off] : 0;
        __syncthreads();
        ls[t] += v;
        __syncthreads();
    }
    int excl = ls[t] - tsum;
    if (idx + 0 < n) bb[idx + 0] = excl;
    if (idx + 1 < n) bb[idx + 1] = excl + a0;
    if (idx + 2 < n) bb[idx + 2] = excl + a0 + a1;
    if (idx + 3 < n) bb[idx + 3] = excl + a0 + a1 + a2;
    if (t == 0) bb[n] = total;
}

// Copy each block's bucket runs to their exact global (bucket-contiguous) slot.
__global__ __launch_bounds__(256) void reorder(
    const int2* __restrict__ recs_tmp, const int* __restrict__ lscan,
    const int* __restrict__ goff_T, const int* __restrict__ bb,
    int2* __restrict__ out) {
    const int b = blockIdx.x, t = threadIdx.x;
    const int* lp = lscan + (size_t)b * LSTRIDE;
    const int2* rp = recs_tmp + (size_t)b * EPB;
    for (int k = t; k < NB; k += 256) {
        int j0 = lp[k], j1 = lp[k + 1];
        int dst = bb[k] + goff_T[(size_t)k * AB2 + b];
        for (int j = j0; j < j1; ++j) out[dst + (j - j0)] = rp[j];
    }
}

// ---------------- segment sum: one block per bucket, contiguous records ----------------

template <int DSHIFT, int DL>
__global__ __launch_bounds__(256) void gatherK(
    const int* __restrict__ bb, const int2* __restrict__ recs,
    const __half* __restrict__ src16, float* __restrict__ dst, int nrows) {
    __shared__ float acc[DL][33];
    const int t = threadIdx.x, g = t >> 5, f = t & 31;
    float* accf = &acc[0][0];
    for (int i = t; i < DL * 33; i += 256) accf[i] = 0.0f;
    __syncthreads();
    const int k = blockIdx.x;
    const int j1 = bb[k + 1];
    int j = bb[k] + g;
    for (; j + 8 < j1; j += 16) {
        int2 ra = recs[j], rb = recs[j + 8];
        float xa = __half2float(src16[(size_t)(ra.x & 0xFFFFF) * FM + f]);
        float xb = __half2float(src16[(size_t)(rb.x & 0xFFFFF) * FM + f]);
        atomicAdd(&acc[ra.x >> 20][f], xa * __int_as_float(ra.y));
        atomicAdd(&acc[rb.x >> 20][f], xb * __int_as_float(rb.y));
    }
    for (; j < j1; j += 8) {
        int2 ra = recs[j];
        float xa = __half2float(src16[(size_t)(ra.x & 0xFFFFF) * FM + f]);
        atomicAdd(&acc[ra.x >> 20][f], xa * __int_as_float(ra.y));
    }
    __syncthreads();
    const int d0 = k << DSHIFT;
    for (int r = g; r < DL; r += 8) {
        int row = d0 + r;
        if (row < nrows) dst[(size_t)row * FM + f] = acc[r][f];
    }
}

// ---------------- fallback atomic scatter (used only if ws too small) ----------------

__global__ __launch_bounds__(256) void scatter_edges(
    const int* __restrict__ src_idx, const int* __restrict__ dst_idx,
    const float* __restrict__ ev, const float* __restrict__ src,
    float* __restrict__ dst, int n_edges) {
    int e = blockIdx.x * 8 + (threadIdx.x >> 5);
    int f = threadIdx.x & 31;
    if (e >= n_edges) return;
    atomicAdd(&dst[(size_t)dst_idx[e] * FM + f], src[(size_t)src_idx[e] * FM + f] * ev[e]);
}

// ---------------- MLP + LayerNorm kernels ----------------

// scalar -> 64 (relu) -> 32, LN. Writes emb and cons (fp32).
__global__ __launch_bounds__(256) void pc_mlp(
    const float* __restrict__ cond,
    const float* __restrict__ W1, const float* __restrict__ b1,
    const float* __restrict__ W2, const float* __restrict__ b2,
    float* __restrict__ dst, float* __restrict__ dst2, int nrows) {
    __shared__ float sW2[64 * FM];
    __shared__ float sh[4][64];
    for (int i = threadIdx.x; i < 64 * FM; i += 256) sW2[i] = W2[i];
    int g = threadIdx.x >> 6, l = threadIdx.x & 63, l32 = l & 31, half = l >> 5;
    float w1l = W1[l], b1l = b1[l], b2l = b2[l32];
    __syncthreads();
    for (int row = blockIdx.x * 4 + g; row < nrows; row += gridDim.x * 4) {
        float c = cond[row];
        sh[g][l] = fmaxf(fmaf(c, w1l, b1l), 0.0f);
        float y = 0.0f;
#pragma unroll
        for (int k = 0; k < 32; k += 4) {
            float4 hv = *(const float4*)&sh[g][half * 32 + k];
            y = fmaf(hv.x, sW2[(half * 32 + k + 0) * FM + l32], y);
            y = fmaf(hv.y, sW2[(half * 32 + k + 1) * FM + l32], y);
            y = fmaf(hv.z, sW2[(half * 32 + k + 2) * FM + l32], y);
            y = fmaf(hv.w, sW2[(half * 32 + k + 3) * FM + l32], y);
        }
        y += __shfl_xor(y, 32);
        y += b2l;
        float s = warp_sum32(y);
        float mu = s * (1.0f / 32.0f);
        float d = y - mu;
        float v = warp_sum32(d * d);
        if (half == 0) {
            float o = d * rsqrtf(v * (1.0f / 32.0f) + LN_EPS);
            dst[(size_t)row * FM + l32] = o;
            dst2[(size_t)row * FM + l32] = o;
        }
    }
}

// IN = NSEG*32 -> 64 (relu) -> 32, LN. Optional fp16 shadow output.
template <int NSEG>
__global__ __launch_bounds__(256) void mlp_ln(
    const float* __restrict__ s0, const float* __restrict__ s1,
    const float* __restrict__ s2,
    const float* __restrict__ W1, const float* __restrict__ b1,
    const float* __restrict__ W2, const float* __restrict__ b2,
    float* __restrict__ dst, __half* __restrict__ dst16, int nrows) {
    constexpr int IN = NSEG * FM;
    __shared__ float sW1[IN * 64];
    __shared__ float sW2[64 * FM];
    __shared__ float sx[4][IN];
    __shared__ float sh[4][64];
    for (int i = threadIdx.x; i < IN * 64; i += 256) sW1[i] = W1[i];
    for (int i = threadIdx.x; i < 64 * FM; i += 256) sW2[i] = W2[i];
    int g = threadIdx.x >> 6, l = threadIdx.x & 63, l32 = l & 31, half = l >> 5;
    float b1l = b1[l], b2l = b2[l32];
    __syncthreads();
    for (int row = blockIdx.x * 4 + g; row < nrows; row += gridDim.x * 4) {
#pragma unroll
        for (int i = l; i < IN; i += 64) {
            const float* s = (i < 32) ? s0 : (i < 64) ? s1 : s2;
            sx[g][i] = s[(size_t)row * FM + (i & 31)];
        }
        float acc = b1l;
#pragma unroll
        for (int k = 0; k < IN; k += 4) {
            float4 xv = *(const float4*)&sx[g][k];
            acc = fmaf(xv.x, sW1[(k + 0) * 64 + l], acc);
            acc = fmaf(xv.y, sW1[(k + 1) * 64 + l], acc);
            acc = fmaf(xv.z, sW1[(k + 2) * 64 + l], acc);
            acc = fmaf(xv.w, sW1[(k + 3) * 64 + l], acc);
        }
        sh[g][l] = fmaxf(acc, 0.0f);
        float y = 0.0f;
#pragma unroll
        for (int k = 0; k < 32; k += 4) {
            float4 hv = *(const float4*)&sh[g][half * 32 + k];
            y = fmaf(hv.x, sW2[(half * 32 + k + 0) * FM + l32], y);
            y = fmaf(hv.y, sW2[(half * 32 + k + 1) * FM + l32], y);
            y = fmaf(hv.z, sW2[(half * 32 + k + 2) * FM + l32], y);
            y = fmaf(hv.w, sW2[(half * 32 + k + 3) * FM + l32], y);
        }
        y += __shfl_xor(y, 32);
        y += b2l;
        float s = warp_sum32(y);
        float mu = s * (1.0f / 32.0f);
        float d = y - mu;
        float v = warp_sum32(d * d);
        if (half == 0) {
            float o = d * rsqrtf(v * (1.0f / 32.0f) + LN_EPS);
            dst[(size_t)row * FM + l32] = o;
            if (dst16) dst16[(size_t)row * FM + l32] = __float2half(o);
        }
    }
}

// 32 -> 64 (relu) -> 16, sigmoid.
__global__ __launch_bounds__(256) void out_mlp(
    const float* __restrict__ x,
    const float* __restrict__ W1, const float* __restrict__ b1,
    const float* __restrict__ W2, const float* __restrict__ b2,
    float* __restrict__ dst, int nrows) {
    __shared__ float sW1[FM * 64];
    __shared__ float sW2[64 * 16];
    __shared__ float sx[4][FM];
    __shared__ float sh[4][64];
    for (int i = threadIdx.x; i < FM * 64; i += 256) sW1[i] = W1[i];
    for (int i = threadIdx.x; i < 64 * 16; i += 256) sW2[i] = W2[i];
    int g = threadIdx.x >> 6, l = threadIdx.x & 63;
    int o = l & 15, q = l >> 4;
    float b1l = b1[l];
    float b2o = b2[o];
    __syncthreads();
    for (int row = blockIdx.x * 4 + g; row < nrows; row += gridDim.x * 4) {
        if (l < FM) sx[g][l] = x[(size_t)row * FM + l];
        float acc = b1l;
#pragma unroll
        for (int k = 0; k < FM; k += 4) {
            float4 xv = *(const float4*)&sx[g][k];
            acc = fmaf(xv.x, sW1[(k + 0) * 64 + l], acc);
            acc = fmaf(xv.y, sW1[(k + 1) * 64 + l], acc);
            acc = fmaf(xv.z, sW1[(k + 2) * 64 + l], acc);
            acc = fmaf(xv.w, sW1[(k + 3) * 64 + l], acc);
        }
        sh[g][l] = fmaxf(acc, 0.0f);
        float y = 0.0f;
#pragma unroll
        for (int k = 0; k < 16; k += 4) {
            int kk = q * 16 + k;
            float4 hv = *(const float4*)&sh[g][kk];
            y = fmaf(hv.x, sW2[(kk + 0) * 16 + o], y);
            y = fmaf(hv.y, sW2[(kk + 1) * 16 + o], y);
            y = fmaf(hv.z, sW2[(kk + 2) * 16 + o], y);
            y = fmaf(hv.w, sW2[(kk + 3) * 16 + o], y);
        }
        y += __shfl_xor(y, 16);
        y += __shfl_xor(y, 32);
        if (q == 0) dst[(size_t)row * 16 + o] = 1.0f / (1.0f + expf(-(y + b2o)));
    }
}

// ---------------- launcher ----------------

extern "C" void kernel_launch(void* const* d_in, const int* in_sizes, int n_in,
                              void* d_out, int out_size, void* d_ws, size_t ws_size,
                              hipStream_t stream) {
    const int*   edge_var   = (const int*)d_in[0];
    const int*   edge_const = (const int*)d_in[1];
    const float* edge_val   = (const float*)d_in[2];
    const float* cond       = (const float*)d_in[3];
    const float* pc_W1 = (const float*)d_in[6];
    const float* pc_b1 = (const float*)d_in[7];
    const float* pc_W2 = (const float*)d_in[8];
    const float* pc_b2 = (const float*)d_in[9];
    const float* cu_W1 = (const float*)d_in[10];
    const float* cu_b1 = (const float*)d_in[11];
    const float* cu_W2 = (const float*)d_in[12];
    const float* cu_b2 = (const float*)d_in[13];
    const float* vu_W1 = (const float*)d_in[14];
    const float* vu_b1 = (const float*)d_in[15];
    const float* vu_W2 = (const float*)d_in[16];
    const float* vu_b2 = (const float*)d_in[17];
    const float* out_W1 = (const float*)d_in[18];
    const float* out_b1 = (const float*)d_in[19];
    const float* out_W2 = (const float*)d_in[20];
    const float* out_b2 = (const float*)d_in[21];

    float* ws = (float*)d_ws;
    size_t off = 0;
    auto alloc = [&](size_t nelems) {
        float* p = ws + off;
        off += (nelems + 15) & ~(size_t)15;
        return p;
    };
    float*  emb     = alloc(CONST_COUNT * FM);
    float*  cons    = alloc(CONST_COUNT * FM);
    float*  vars    = alloc(VAR_COUNT * FM);
    float*  msg     = alloc(VAR_COUNT * FM);
    __half* vars16  = (__half*)alloc(VAR_COUNT * FM / 2);
    __half* cons16  = (__half*)alloc(CONST_COUNT * FM / 2);
    int2*   recs_c  = (int2*)alloc((size_t)N_EDGES * 2);
    int2*   recs_v  = (int2*)alloc((size_t)N_EDGES * 2);
    int2*   recs_t  = (int2*)alloc((size_t)N_EDGES * 2);
    int*    lscan   = (int*)alloc((size_t)ABLK * LSTRIDE);
    int*    rlen_T  = (int*)alloc((size_t)NB * AB2);
    int*    goff_T  = (int*)alloc((size_t)NB * AB2);
    int*    btot    = (int*)alloc(NB);
    int*    bb_c    = (int*)alloc(NB + 1);
    int*    bb_v    = (int*)alloc(NB + 1);
    size_t need_bytes = off * sizeof(float);
    bool fast = ws_size >= need_bytes;

    if (fast) {
        // --- build bucket-contiguous sorted edge lists, both directions ---
        // const-direction (dest = edge_const, 64 dests/bucket)
        bucket_sort<6><<<ABLK, 256, 0, stream>>>(edge_const, edge_var, edge_val,
                                                 recs_t, lscan, rlen_T, N_EDGES);
        scan_cols<<<NB, 256, 0, stream>>>(rlen_T, goff_T, btot);
        scan_btot<<<1, 256, 0, stream>>>(btot, bb_c, NB, N_EDGES);
        reorder<<<ABLK, 256, 0, stream>>>(recs_t, lscan, goff_T, bb_c, recs_c);
        // var-direction (dest = edge_var, 128 dests/bucket)
        bucket_sort<7><<<ABLK, 256, 0, stream>>>(edge_var, edge_const, edge_val,
                                                 recs_t, lscan, rlen_T, N_EDGES);
        scan_cols<<<NB, 256, 0, stream>>>(rlen_T, goff_T, btot);
        scan_btot<<<1, 256, 0, stream>>>(btot, bb_v, NB, N_EDGES);
        reorder<<<ABLK, 256, 0, stream>>>(recs_t, lscan, goff_T, bb_v, recs_v);
    }

    init_vars<<<(VAR_COUNT * FM + 255) / 256, 256, 0, stream>>>(
        vars, fast ? vars16 : nullptr, VAR_COUNT * FM);
    pc_mlp<<<1024, 256, 0, stream>>>(cond, pc_W1, pc_b1, pc_W2, pc_b2, emb, cons,
                                     CONST_COUNT);

    for (int pass = 0; pass < 3; ++pass) {
        if (fast) {
            gatherK<6, 64><<<NB, 256, 0, stream>>>(bb_c, recs_c, vars16, msg, CONST_COUNT);
        } else {
            hipMemsetAsync(msg, 0, (size_t)CONST_COUNT * FM * sizeof(float), stream);
            scatter_edges<<<N_EDGES / 8, 256, 0, stream>>>(edge_var, edge_const, edge_val,
                                                           vars, msg, N_EDGES);
        }
        mlp_ln<3><<<1024, 256, 0, stream>>>(cons, emb, msg, cu_W1, cu_b1, cu_W2, cu_b2,
                                            cons, fast ? cons16 : nullptr, CONST_COUNT);
        if (fast) {
            gatherK<7, 128><<<NB, 256, 0, stream>>>(bb_v, recs_v, cons16, msg, VAR_COUNT);
        } else {
            hipMemsetAsync(msg, 0, (size_t)VAR_COUNT * FM * sizeof(float), stream);
            scatter_edges<<<N_EDGES / 8, 256, 0, stream>>>(edge_const, edge_var, edge_val,
                                                           cons, msg, N_EDGES);
        }
        mlp_ln<2><<<1024, 256, 0, stream>>>(vars, msg, nullptr, vu_W1, vu_b1, vu_W2, vu_b2,
                                            vars, fast ? vars16 : nullptr, VAR_COUNT);
    }

    out_mlp<<<1024, 256, 0, stream>>>(vars, out_W1, out_b1, out_W2, out_b2,
                                      (float*)d_out, VAR_COUNT);
}

// Round 5
// 942.584 us; speedup vs baseline: 4.7925x; 4.7149x over previous
//
#include <hip/hip_runtime.h>
#include <hip/hip_fp16.h>
#include <math.h>

#define FM 32
#define N_EDGES 3200000
#define VAR_COUNT 100000
#define CONST_COUNT 50000
#define LN_EPS 1e-5f

#define EPB 4096                 // edges per sort block
#define ABLK 782                 // ceil(N_EDGES / EPB)
#define NB 782                   // buckets (64 consts or 128 vars each)
#define AB2 784                  // padded stride for transposed rlen matrix
#define LSTRIDE 784              // NB + 2
#define CAP 4608                 // max records per bucket staged in LDS (+8 sigma)

static __device__ __forceinline__ float warp_sum32(float v) {
#pragma unroll
    for (int m = 16; m; m >>= 1) v += __shfl_xor(v, m);
    return v;
}

__global__ void init_vars(float* __restrict__ v, __half* __restrict__ v16, int n) {
    int i = blockIdx.x * 256 + threadIdx.x;
    if (i < n) { v[i] = 1.0f; if (v16) v16[i] = __float2half(1.0f); }
}

// ---------------- block-local bucket sort (no global atomics) ----------------
// Block owns edges [blk*EPB, blk*EPB+nb); writes records grouped by bucket
// (dest >> DSHIFT) to recs_tmp[blk*EPB...], per-block bucket start offsets to
// lscan[blk][k], and run lengths transposed to rlen_T[k][blk].

template <int DSHIFT>
__global__ __launch_bounds__(256) void bucket_sort(
    const int* __restrict__ dest_arr, const int* __restrict__ src_arr,
    const float* __restrict__ val_arr,
    int2* __restrict__ recs_tmp, int* __restrict__ lscan, int* __restrict__ rlen_T,
    int n) {
    __shared__ int hist[NB];
    __shared__ int cursor[NB];
    __shared__ int chunk[256];
    __shared__ int2 stage[EPB];
    const int t = threadIdx.x;
    const int base = blockIdx.x * EPB;
    const int nb = min(EPB, n - base);
    for (int i = t; i < NB; i += 256) hist[i] = 0;
    __syncthreads();
    int dg[16], pk[16], vb[16];
#pragma unroll
    for (int k = 0; k < 16; ++k) {
        int j = k * 256 + t;
        dg[k] = -1;
        if (j < nb) {
            int dest = dest_arr[base + j];
            int src  = src_arr[base + j];
            vb[k] = __float_as_int(val_arr[base + j]);
            dg[k] = dest >> DSHIFT;
            pk[k] = ((dest & ((1 << DSHIFT) - 1)) << 20) | src;
            atomicAdd(&hist[dg[k]], 1);
        }
    }
    __syncthreads();
    int sum = 0;
#pragma unroll
    for (int k = 0; k < 4; ++k) {
        int idx = t * 4 + k;
        if (idx < NB) sum += hist[idx];
    }
    chunk[t] = sum;
    __syncthreads();
    for (int off = 1; off < 256; off <<= 1) {
        int v = (t >= off) ? chunk[t - off] : 0;
        __syncthreads();
        chunk[t] += v;
        __syncthreads();
    }
    int run = chunk[t] - sum;
#pragma unroll
    for (int k = 0; k < 4; ++k) {
        int idx = t * 4 + k;
        if (idx < NB) {
            int h = hist[idx];
            rlen_T[(size_t)idx * AB2 + blockIdx.x] = h;
            hist[idx] = run;
            cursor[idx] = run;
            run += h;
        }
    }
    __syncthreads();
    {
        int* lp = lscan + (size_t)blockIdx.x * LSTRIDE;
        for (int i = t; i < NB; i += 256) lp[i] = hist[i];
        if (t == 0) lp[NB] = nb;
    }
#pragma unroll
    for (int k = 0; k < 16; ++k) {
        if (dg[k] >= 0) {
            int pos = atomicAdd(&cursor[dg[k]], 1);
            stage[pos] = make_int2(pk[k], vb[k]);
        }
    }
    __syncthreads();
    for (int j = t; j < nb; j += 256) recs_tmp[(size_t)base + j] = stage[j];
}

// Bucket totals: btot[k] = sum_b rlen_T[k][b] (coalesced row sum).
__global__ __launch_bounds__(256) void row_sum(const int* __restrict__ rlen_T,
                                               int* __restrict__ btot) {
    __shared__ int ls[256];
    const int t = threadIdx.x;
    const int* rp = rlen_T + (size_t)blockIdx.x * AB2;
    int s = 0;
    for (int b = t; b < ABLK; b += 256) s += rp[b];
    ls[t] = s;
    __syncthreads();
    for (int off = 128; off; off >>= 1) {
        if (t < off) ls[t] += ls[t + off];
        __syncthreads();
    }
    if (t == 0) btot[blockIdx.x] = ls[0];
}

// Exclusive scan of bucket totals -> bucket base offsets bb[0..NB], bb[NB]=total.
__global__ __launch_bounds__(256) void scan_btot(
    const int* __restrict__ btot, int* __restrict__ bb, int n, int total) {
    __shared__ int ls[256];
    const int t = threadIdx.x;
    int idx = t * 4;
    int a0 = (idx + 0 < n) ? btot[idx + 0] : 0;
    int a1 = (idx + 1 < n) ? btot[idx + 1] : 0;
    int a2 = (idx + 2 < n) ? btot[idx + 2] : 0;
    int a3 = (idx + 3 < n) ? btot[idx + 3] : 0;
    int tsum = a0 + a1 + a2 + a3;
    ls[t] = tsum;
    __syncthreads();
    for (int off = 1; off < 256; off <<= 1) {
        int v = (t >= off) ? ls[t - off] : 0;
        __syncthreads();
        ls[t] += v;
        __syncthreads();
    }
    int excl = ls[t] - tsum;
    if (idx + 0 < n) bb[idx + 0] = excl;
    if (idx + 1 < n) bb[idx + 1] = excl + a0;
    if (idx + 2 < n) bb[idx + 2] = excl + a0 + a1;
    if (idx + 3 < n) bb[idx + 3] = excl + a0 + a1 + a2;
    if (t == 0) bb[n] = total;
}

// ---------------- collect + final counting sort per bucket ----------------
// Block k gathers its bucket's runs from all sort blocks into LDS, sorts by
// destination (LDS counting sort), writes dest-contiguous records coalesced
// at bb[k], and writes the per-destination offs array.

template <int DSHIFT, int NDEST>
__global__ __launch_bounds__(256) void collect_sort(
    const int2* __restrict__ recs_tmp, const int* __restrict__ lscan,
    const int* __restrict__ rlen_T, const int* __restrict__ bb,
    int2* __restrict__ recs_out, int* __restrict__ offs, int nrows) {
    __shared__ int2 stage[CAP];
    __shared__ int perm[CAP];
    __shared__ int rloff[256];
    __shared__ int hist[NDEST];
    __shared__ int cursor[NDEST];
    __shared__ int sc[NDEST];
    __shared__ int nb_s;
    const int t = threadIdx.x;
    const int k = blockIdx.x;
    // phase 1: run starts (scattered) + lengths (coalesced), 4 sort-blocks/thread
    const int b0 = t * 4;
    int s0 = 0, s1 = 0, s2 = 0, s3 = 0, l0 = 0, l1 = 0, l2 = 0, l3 = 0;
    if (b0 + 0 < ABLK) { s0 = lscan[(size_t)(b0 + 0) * LSTRIDE + k]; l0 = rlen_T[(size_t)k * AB2 + b0 + 0]; }
    if (b0 + 1 < ABLK) { s1 = lscan[(size_t)(b0 + 1) * LSTRIDE + k]; l1 = rlen_T[(size_t)k * AB2 + b0 + 1]; }
    if (b0 + 2 < ABLK) { s2 = lscan[(size_t)(b0 + 2) * LSTRIDE + k]; l2 = rlen_T[(size_t)k * AB2 + b0 + 2]; }
    if (b0 + 3 < ABLK) { s3 = lscan[(size_t)(b0 + 3) * LSTRIDE + k]; l3 = rlen_T[(size_t)k * AB2 + b0 + 3]; }
    int tsum = l0 + l1 + l2 + l3;
    rloff[t] = tsum;
    __syncthreads();
    for (int off = 1; off < 256; off <<= 1) {
        int v = (t >= off) ? rloff[t - off] : 0;
        __syncthreads();
        rloff[t] += v;
        __syncthreads();
    }
    if (t == 255) nb_s = rloff[255];
    int o0 = rloff[t] - tsum;
    int o1 = o0 + l0, o2 = o1 + l1, o3 = o2 + l2;
    for (int i = t; i < NDEST; i += 256) hist[i] = 0;
    __syncthreads();
    const int nb = min(nb_s, CAP);
    // phase 2: copy runs into LDS stage (reads L2/LLC-resident, writes LDS)
    {
        const int2* rp = recs_tmp + (size_t)(b0 + 0) * EPB + s0;
        for (int j = 0; j < l0; ++j) if (o0 + j < CAP) stage[o0 + j] = rp[j];
        rp = recs_tmp + (size_t)(b0 + 1) * EPB + s1;
        for (int j = 0; j < l1; ++j) if (o1 + j < CAP) stage[o1 + j] = rp[j];
        rp = recs_tmp + (size_t)(b0 + 2) * EPB + s2;
        for (int j = 0; j < l2; ++j) if (o2 + j < CAP) stage[o2 + j] = rp[j];
        rp = recs_tmp + (size_t)(b0 + 3) * EPB + s3;
        for (int j = 0; j < l3; ++j) if (o3 + j < CAP) stage[o3 + j] = rp[j];
    }
    __syncthreads();
    // phase 3: histogram by local dest
    for (int j = t; j < nb; j += 256) atomicAdd(&hist[stage[j].x >> 20], 1);
    __syncthreads();
    // phase 4: scan hist -> exclusive offsets; write offs
    if (t < NDEST) sc[t] = hist[t];
    __syncthreads();
    for (int off = 1; off < NDEST; off <<= 1) {
        int v = (t >= off && t < NDEST) ? sc[t - off] : 0;
        __syncthreads();
        if (t < NDEST) sc[t] += v;
        __syncthreads();
    }
    if (t < NDEST) {
        int excl = sc[t] - hist[t];
        cursor[t] = excl;
        int gd = (k << DSHIFT) + t;
        if (gd <= nrows) offs[gd] = bb[k] + excl;
    }
    __syncthreads();
    // phase 5: rank (order within dest arbitrary)
    for (int j = t; j < nb; j += 256) {
        int pos = atomicAdd(&cursor[stage[j].x >> 20], 1);
        perm[pos] = j;
    }
    __syncthreads();
    // phase 6: coalesced global write of sorted records (strip dest bits)
    const int base_out = bb[k];
    for (int j = t; j < nb; j += 256) {
        int2 r = stage[perm[j]];
        recs_out[(size_t)base_out + j] = make_int2(r.x & 0xFFFFF, r.y);
    }
}

// ---------------- segment sum via per-dest register gather (fp16 sources) ----------------

__global__ __launch_bounds__(256) void seg_gather16(
    const int* __restrict__ offs, const int2* __restrict__ recs,
    const __half* __restrict__ src16, float* __restrict__ dst, int nrows) {
    int g = threadIdx.x >> 5, f = threadIdx.x & 31;
    int row = blockIdx.x * 8 + g;
    if (row >= nrows) return;
    int j = offs[row], j1 = offs[row + 1];
    float acc0 = 0.0f, acc1 = 0.0f;
    for (; j + 2 <= j1; j += 2) {
        int2 a = recs[j];
        int2 b = recs[j + 1];
        acc0 = fmaf(__half2float(src16[(size_t)a.x * FM + f]), __int_as_float(a.y), acc0);
        acc1 = fmaf(__half2float(src16[(size_t)b.x * FM + f]), __int_as_float(b.y), acc1);
    }
    if (j < j1) {
        int2 a = recs[j];
        acc0 = fmaf(__half2float(src16[(size_t)a.x * FM + f]), __int_as_float(a.y), acc0);
    }
    dst[(size_t)row * FM + f] = acc0 + acc1;
}

// ---------------- fallback atomic scatter (used only if ws too small) ----------------

__global__ __launch_bounds__(256) void scatter_edges(
    const int* __restrict__ src_idx, const int* __restrict__ dst_idx,
    const float* __restrict__ ev, const float* __restrict__ src,
    float* __restrict__ dst, int n_edges) {
    int e = blockIdx.x * 8 + (threadIdx.x >> 5);
    int f = threadIdx.x & 31;
    if (e >= n_edges) return;
    atomicAdd(&dst[(size_t)dst_idx[e] * FM + f], src[(size_t)src_idx[e] * FM + f] * ev[e]);
}

// ---------------- MLP + LayerNorm kernels ----------------

__global__ __launch_bounds__(256) void pc_mlp(
    const float* __restrict__ cond,
    const float* __restrict__ W1, const float* __restrict__ b1,
    const float* __restrict__ W2, const float* __restrict__ b2,
    float* __restrict__ dst, float* __restrict__ dst2, int nrows) {
    __shared__ float sW2[64 * FM];
    __shared__ float sh[4][64];
    for (int i = threadIdx.x; i < 64 * FM; i += 256) sW2[i] = W2[i];
    int g = threadIdx.x >> 6, l = threadIdx.x & 63, l32 = l & 31, half = l >> 5;
    float w1l = W1[l], b1l = b1[l], b2l = b2[l32];
    __syncthreads();
    for (int row = blockIdx.x * 4 + g; row < nrows; row += gridDim.x * 4) {
        float c = cond[row];
        sh[g][l] = fmaxf(fmaf(c, w1l, b1l), 0.0f);
        float y = 0.0f;
#pragma unroll
        for (int k = 0; k < 32; k += 4) {
            float4 hv = *(const float4*)&sh[g][half * 32 + k];
            y = fmaf(hv.x, sW2[(half * 32 + k + 0) * FM + l32], y);
            y = fmaf(hv.y, sW2[(half * 32 + k + 1) * FM + l32], y);
            y = fmaf(hv.z, sW2[(half * 32 + k + 2) * FM + l32], y);
            y = fmaf(hv.w, sW2[(half * 32 + k + 3) * FM + l32], y);
        }
        y += __shfl_xor(y, 32);
        y += b2l;
        float s = warp_sum32(y);
        float mu = s * (1.0f / 32.0f);
        float d = y - mu;
        float v = warp_sum32(d * d);
        if (half == 0) {
            float o = d * rsqrtf(v * (1.0f / 32.0f) + LN_EPS);
            dst[(size_t)row * FM + l32] = o;
            dst2[(size_t)row * FM + l32] = o;
        }
    }
}

template <int NSEG>
__global__ __launch_bounds__(256) void mlp_ln(
    const float* __restrict__ s0, const float* __restrict__ s1,
    const float* __restrict__ s2,
    const float* __restrict__ W1, const float* __restrict__ b1,
    const float* __restrict__ W2, const float* __restrict__ b2,
    float* __restrict__ dst, __half* __restrict__ dst16, int nrows) {
    constexpr int IN = NSEG * FM;
    __shared__ float sW1[IN * 64];
    __shared__ float sW2[64 * FM];
    __shared__ float sx[4][IN];
    __shared__ float sh[4][64];
    for (int i = threadIdx.x; i < IN * 64; i += 256) sW1[i] = W1[i];
    for (int i = threadIdx.x; i < 64 * FM; i += 256) sW2[i] = W2[i];
    int g = threadIdx.x >> 6, l = threadIdx.x & 63, l32 = l & 31, half = l >> 5;
    float b1l = b1[l], b2l = b2[l32];
    __syncthreads();
    for (int row = blockIdx.x * 4 + g; row < nrows; row += gridDim.x * 4) {
#pragma unroll
        for (int i = l; i < IN; i += 64) {
            const float* s = (i < 32) ? s0 : (i < 64) ? s1 : s2;
            sx[g][i] = s[(size_t)row * FM + (i & 31)];
        }
        float acc = b1l;
#pragma unroll
        for (int k = 0; k < IN; k += 4) {
            float4 xv = *(const float4*)&sx[g][k];
            acc = fmaf(xv.x, sW1[(k + 0) * 64 + l], acc);
            acc = fmaf(xv.y, sW1[(k + 1) * 64 + l], acc);
            acc = fmaf(xv.z, sW1[(k + 2) * 64 + l], acc);
            acc = fmaf(xv.w, sW1[(k + 3) * 64 + l], acc);
        }
        sh[g][l] = fmaxf(acc, 0.0f);
        float y = 0.0f;
#pragma unroll
        for (int k = 0; k < 32; k += 4) {
            float4 hv = *(const float4*)&sh[g][half * 32 + k];
            y = fmaf(hv.x, sW2[(half * 32 + k + 0) * FM + l32], y);
            y = fmaf(hv.y, sW2[(half * 32 + k + 1) * FM + l32], y);
            y = fmaf(hv.z, sW2[(half * 32 + k + 2) * FM + l32], y);
            y = fmaf(hv.w, sW2[(half * 32 + k + 3) * FM + l32], y);
        }
        y += __shfl_xor(y, 32);
        y += b2l;
        float s = warp_sum32(y);
        float mu = s * (1.0f / 32.0f);
        float d = y - mu;
        float v = warp_sum32(d * d);
        if (half == 0) {
            float o = d * rsqrtf(v * (1.0f / 32.0f) + LN_EPS);
            dst[(size_t)row * FM + l32] = o;
            if (dst16) dst16[(size_t)row * FM + l32] = __float2half(o);
        }
    }
}

__global__ __launch_bounds__(256) void out_mlp(
    const float* __restrict__ x,
    const float* __restrict__ W1, const float* __restrict__ b1,
    const float* __restrict__ W2, const float* __restrict__ b2,
    float* __restrict__ dst, int nrows) {
    __shared__ float sW1[FM * 64];
    __shared__ float sW2[64 * 16];
    __shared__ float sx[4][FM];
    __shared__ float sh[4][64];
    for (int i = threadIdx.x; i < FM * 64; i += 256) sW1[i] = W1[i];
    for (int i = threadIdx.x; i < 64 * 16; i += 256) sW2[i] = W2[i];
    int g = threadIdx.x >> 6, l = threadIdx.x & 63;
    int o = l & 15, q = l >> 4;
    float b1l = b1[l];
    float b2o = b2[o];
    __syncthreads();
    for (int row = blockIdx.x * 4 + g; row < nrows; row += gridDim.x * 4) {
        if (l < FM) sx[g][l] = x[(size_t)row * FM + l];
        float acc = b1l;
#pragma unroll
        for (int k = 0; k < FM; k += 4) {
            float4 xv = *(const float4*)&sx[g][k];
            acc = fmaf(xv.x, sW1[(k + 0) * 64 + l], acc);
            acc = fmaf(xv.y, sW1[(k + 1) * 64 + l], acc);
            acc = fmaf(xv.z, sW1[(k + 2) * 64 + l], acc);
            acc = fmaf(xv.w, sW1[(k + 3) * 64 + l], acc);
        }
        sh[g][l] = fmaxf(acc, 0.0f);
        float y = 0.0f;
#pragma unroll
        for (int k = 0; k < 16; k += 4) {
            int kk = q * 16 + k;
            float4 hv = *(const float4*)&sh[g][kk];
            y = fmaf(hv.x, sW2[(kk + 0) * 16 + o], y);
            y = fmaf(hv.y, sW2[(kk + 1) * 16 + o], y);
            y = fmaf(hv.z, sW2[(kk + 2) * 16 + o], y);
            y = fmaf(hv.w, sW2[(kk + 3) * 16 + o], y);
        }
        y += __shfl_xor(y, 16);
        y += __shfl_xor(y, 32);
        if (q == 0) dst[(size_t)row * 16 + o] = 1.0f / (1.0f + expf(-(y + b2o)));
    }
}

// ---------------- launcher ----------------

extern "C" void kernel_launch(void* const* d_in, const int* in_sizes, int n_in,
                              void* d_out, int out_size, void* d_ws, size_t ws_size,
                              hipStream_t stream) {
    const int*   edge_var   = (const int*)d_in[0];
    const int*   edge_const = (const int*)d_in[1];
    const float* edge_val   = (const float*)d_in[2];
    const float* cond       = (const float*)d_in[3];
    const float* pc_W1 = (const float*)d_in[6];
    const float* pc_b1 = (const float*)d_in[7];
    const float* pc_W2 = (const float*)d_in[8];
    const float* pc_b2 = (const float*)d_in[9];
    const float* cu_W1 = (const float*)d_in[10];
    const float* cu_b1 = (const float*)d_in[11];
    const float* cu_W2 = (const float*)d_in[12];
    const float* cu_b2 = (const float*)d_in[13];
    const float* vu_W1 = (const float*)d_in[14];
    const float* vu_b1 = (const float*)d_in[15];
    const float* vu_W2 = (const float*)d_in[16];
    const float* vu_b2 = (const float*)d_in[17];
    const float* out_W1 = (const float*)d_in[18];
    const float* out_b1 = (const float*)d_in[19];
    const float* out_W2 = (const float*)d_in[20];
    const float* out_b2 = (const float*)d_in[21];

    float* ws = (float*)d_ws;
    size_t off = 0;
    auto alloc = [&](size_t nelems) {
        float* p = ws + off;
        off += (nelems + 15) & ~(size_t)15;
        return p;
    };
    float*  emb    = alloc(CONST_COUNT * FM);
    float*  cons   = alloc(CONST_COUNT * FM);
    float*  vars   = alloc(VAR_COUNT * FM);
    float*  msg    = alloc(VAR_COUNT * FM);
    __half* vars16 = (__half*)alloc(VAR_COUNT * FM / 2);
    __half* cons16 = (__half*)alloc(CONST_COUNT * FM / 2);
    int2*   recs_t = (int2*)alloc((size_t)N_EDGES * 2);
    int2*   recs_c = (int2*)alloc((size_t)N_EDGES * 2);
    int2*   recs_v = (int2*)alloc((size_t)N_EDGES * 2);
    int*    lscan  = (int*)alloc((size_t)ABLK * LSTRIDE);
    int*    rlen_T = (int*)alloc((size_t)NB * AB2);
    int*    btot   = (int*)alloc(NB);
    int*    bb_c   = (int*)alloc(NB + 1);
    int*    bb_v   = (int*)alloc(NB + 1);
    int*    offs_c = (int*)alloc(CONST_COUNT + 1);
    int*    offs_v = (int*)alloc(VAR_COUNT + 1);
    size_t need_bytes = off * sizeof(float);
    bool fast = ws_size >= need_bytes;

    if (fast) {
        // const-direction: dest = edge_const (64 dests/bucket)
        bucket_sort<6><<<ABLK, 256, 0, stream>>>(edge_const, edge_var, edge_val,
                                                 recs_t, lscan, rlen_T, N_EDGES);
        row_sum<<<NB, 256, 0, stream>>>(rlen_T, btot);
        scan_btot<<<1, 256, 0, stream>>>(btot, bb_c, NB, N_EDGES);
        collect_sort<6, 64><<<NB, 256, 0, stream>>>(recs_t, lscan, rlen_T, bb_c,
                                                    recs_c, offs_c, CONST_COUNT);
        // var-direction: dest = edge_var (128 dests/bucket)
        bucket_sort<7><<<ABLK, 256, 0, stream>>>(edge_var, edge_const, edge_val,
                                                 recs_t, lscan, rlen_T, N_EDGES);
        row_sum<<<NB, 256, 0, stream>>>(rlen_T, btot);
        scan_btot<<<1, 256, 0, stream>>>(btot, bb_v, NB, N_EDGES);
        collect_sort<7, 128><<<NB, 256, 0, stream>>>(recs_t, lscan, rlen_T, bb_v,
                                                     recs_v, offs_v, VAR_COUNT);
    }

    init_vars<<<(VAR_COUNT * FM + 255) / 256, 256, 0, stream>>>(
        vars, fast ? vars16 : nullptr, VAR_COUNT * FM);
    pc_mlp<<<1024, 256, 0, stream>>>(cond, pc_W1, pc_b1, pc_W2, pc_b2, emb, cons,
                                     CONST_COUNT);

    for (int pass = 0; pass < 3; ++pass) {
        if (fast) {
            seg_gather16<<<(CONST_COUNT + 7) / 8, 256, 0, stream>>>(
                offs_c, recs_c, vars16, msg, CONST_COUNT);
        } else {
            hipMemsetAsync(msg, 0, (size_t)CONST_COUNT * FM * sizeof(float), stream);
            scatter_edges<<<N_EDGES / 8, 256, 0, stream>>>(edge_var, edge_const, edge_val,
                                                           vars, msg, N_EDGES);
        }
        mlp_ln<3><<<1024, 256, 0, stream>>>(cons, emb, msg, cu_W1, cu_b1, cu_W2, cu_b2,
                                            cons, fast ? cons16 : nullptr, CONST_COUNT);
        if (fast) {
            seg_gather16<<<(VAR_COUNT + 7) / 8, 256, 0, stream>>>(
                offs_v, recs_v, cons16, msg, VAR_COUNT);
        } else {
            hipMemsetAsync(msg, 0, (size_t)VAR_COUNT * FM * sizeof(float), stream);
            scatter_edges<<<N_EDGES / 8, 256, 0, stream>>>(edge_const, edge_var, edge_val,
                                                           cons, msg, N_EDGES);
        }
        mlp_ln<2><<<1024, 256, 0, stream>>>(vars, msg, nullptr, vu_W1, vu_b1, vu_W2, vu_b2,
                                            vars, fast ? vars16 : nullptr, VAR_COUNT);
    }

    out_mlp<<<1024, 256, 0, stream>>>(vars, out_W1, out_b1, out_W2, out_b2,
                                      (float*)d_out, VAR_COUNT);
}

// Round 6
// 694.228 us; speedup vs baseline: 6.5069x; 1.3577x over previous
//
#include <hip/hip_runtime.h>
#include <hip/hip_fp16.h>
#include <math.h>

#define FM 32
#define N_EDGES 3200000
#define VAR_COUNT 100000
#define CONST_COUNT 50000
#define LN_EPS 1e-5f

#define EPB 4096                 // edges per sort block
#define ABLK 782                 // ceil(N_EDGES / EPB)
#define NB 782                   // buckets (64 consts or 128 vars each)
#define AB2 784                  // padded stride for transposed rlen matrix
#define LSTRIDE 784              // NB + 2
#define CAP 4608                 // max records per bucket staged in LDS (+8 sigma)

static __device__ __forceinline__ float warp_sum32(float v) {
#pragma unroll
    for (int m = 16; m; m >>= 1) v += __shfl_xor(v, m);
    return v;
}

__global__ void init_vars(float* __restrict__ v, __half* __restrict__ v16, int n) {
    int i = blockIdx.x * 256 + threadIdx.x;
    if (i < n) { v[i] = 1.0f; if (v16) v16[i] = __float2half(1.0f); }
}

// ---------------- block-local bucket sort (no global atomics) ----------------

template <int DSHIFT>
__global__ __launch_bounds__(256) void bucket_sort(
    const int* __restrict__ dest_arr, const int* __restrict__ src_arr,
    const float* __restrict__ val_arr,
    int2* __restrict__ recs_tmp, int* __restrict__ lscan, int* __restrict__ rlen_T,
    int n) {
    __shared__ int hist[NB];
    __shared__ int cursor[NB];
    __shared__ int chunk[256];
    __shared__ int2 stage[EPB];
    const int t = threadIdx.x;
    const int base = blockIdx.x * EPB;
    const int nb = min(EPB, n - base);
    for (int i = t; i < NB; i += 256) hist[i] = 0;
    __syncthreads();
    int dg[16], pk[16], vb[16];
#pragma unroll
    for (int k = 0; k < 16; ++k) {
        int j = k * 256 + t;
        dg[k] = -1;
        if (j < nb) {
            int dest = dest_arr[base + j];
            int src  = src_arr[base + j];
            vb[k] = __float_as_int(val_arr[base + j]);
            dg[k] = dest >> DSHIFT;
            pk[k] = ((dest & ((1 << DSHIFT) - 1)) << 20) | src;
            atomicAdd(&hist[dg[k]], 1);
        }
    }
    __syncthreads();
    int sum = 0;
#pragma unroll
    for (int k = 0; k < 4; ++k) {
        int idx = t * 4 + k;
        if (idx < NB) sum += hist[idx];
    }
    chunk[t] = sum;
    __syncthreads();
    for (int off = 1; off < 256; off <<= 1) {
        int v = (t >= off) ? chunk[t - off] : 0;
        __syncthreads();
        chunk[t] += v;
        __syncthreads();
    }
    int run = chunk[t] - sum;
#pragma unroll
    for (int k = 0; k < 4; ++k) {
        int idx = t * 4 + k;
        if (idx < NB) {
            int h = hist[idx];
            rlen_T[(size_t)idx * AB2 + blockIdx.x] = h;
            hist[idx] = run;
            cursor[idx] = run;
            run += h;
        }
    }
    __syncthreads();
    {
        int* lp = lscan + (size_t)blockIdx.x * LSTRIDE;
        for (int i = t; i < NB; i += 256) lp[i] = hist[i];
        if (t == 0) lp[NB] = nb;
    }
#pragma unroll
    for (int k = 0; k < 16; ++k) {
        if (dg[k] >= 0) {
            int pos = atomicAdd(&cursor[dg[k]], 1);
            stage[pos] = make_int2(pk[k], vb[k]);
        }
    }
    __syncthreads();
    for (int j = t; j < nb; j += 256) recs_tmp[(size_t)base + j] = stage[j];
}

// Bucket totals: btot[k] = sum_b rlen_T[k][b] (coalesced row sum).
__global__ __launch_bounds__(256) void row_sum(const int* __restrict__ rlen_T,
                                               int* __restrict__ btot) {
    __shared__ int ls[256];
    const int t = threadIdx.x;
    const int* rp = rlen_T + (size_t)blockIdx.x * AB2;
    int s = 0;
    for (int b = t; b < ABLK; b += 256) s += rp[b];
    ls[t] = s;
    __syncthreads();
    for (int off = 128; off; off >>= 1) {
        if (t < off) ls[t] += ls[t + off];
        __syncthreads();
    }
    if (t == 0) btot[blockIdx.x] = ls[0];
}

// Exclusive scan of bucket totals -> bucket base offsets bb[0..NB], bb[NB]=total.
__global__ __launch_bounds__(256) void scan_btot(
    const int* __restrict__ btot, int* __restrict__ bb, int n, int total) {
    __shared__ int ls[256];
    const int t = threadIdx.x;
    int idx = t * 4;
    int a0 = (idx + 0 < n) ? btot[idx + 0] : 0;
    int a1 = (idx + 1 < n) ? btot[idx + 1] : 0;
    int a2 = (idx + 2 < n) ? btot[idx + 2] : 0;
    int a3 = (idx + 3 < n) ? btot[idx + 3] : 0;
    int tsum = a0 + a1 + a2 + a3;
    ls[t] = tsum;
    __syncthreads();
    for (int off = 1; off < 256; off <<= 1) {
        int v = (t >= off) ? ls[t - off] : 0;
        __syncthreads();
        ls[t] += v;
        __syncthreads();
    }
    int excl = ls[t] - tsum;
    if (idx + 0 < n) bb[idx + 0] = excl;
    if (idx + 1 < n) bb[idx + 1] = excl + a0;
    if (idx + 2 < n) bb[idx + 2] = excl + a0 + a1;
    if (idx + 3 < n) bb[idx + 3] = excl + a0 + a1 + a2;
    if (t == 0) bb[n] = total;
}

// ---------------- collect + final counting sort per bucket ----------------

template <int DSHIFT, int NDEST>
__global__ __launch_bounds__(256) void collect_sort(
    const int2* __restrict__ recs_tmp, const int* __restrict__ lscan,
    const int* __restrict__ rlen_T, const int* __restrict__ bb,
    int2* __restrict__ recs_out, int* __restrict__ offs, int nrows) {
    __shared__ int2 stage[CAP];
    __shared__ int perm[CAP];
    __shared__ int rloff[256];
    __shared__ int hist[NDEST];
    __shared__ int cursor[NDEST];
    __shared__ int sc[NDEST];
    __shared__ int nb_s;
    const int t = threadIdx.x;
    const int k = blockIdx.x;
    const int b0 = t * 4;
    int s0 = 0, s1 = 0, s2 = 0, s3 = 0, l0 = 0, l1 = 0, l2 = 0, l3 = 0;
    if (b0 + 0 < ABLK) { s0 = lscan[(size_t)(b0 + 0) * LSTRIDE + k]; l0 = rlen_T[(size_t)k * AB2 + b0 + 0]; }
    if (b0 + 1 < ABLK) { s1 = lscan[(size_t)(b0 + 1) * LSTRIDE + k]; l1 = rlen_T[(size_t)k * AB2 + b0 + 1]; }
    if (b0 + 2 < ABLK) { s2 = lscan[(size_t)(b0 + 2) * LSTRIDE + k]; l2 = rlen_T[(size_t)k * AB2 + b0 + 2]; }
    if (b0 + 3 < ABLK) { s3 = lscan[(size_t)(b0 + 3) * LSTRIDE + k]; l3 = rlen_T[(size_t)k * AB2 + b0 + 3]; }
    int tsum = l0 + l1 + l2 + l3;
    rloff[t] = tsum;
    __syncthreads();
    for (int off = 1; off < 256; off <<= 1) {
        int v = (t >= off) ? rloff[t - off] : 0;
        __syncthreads();
        rloff[t] += v;
        __syncthreads();
    }
    if (t == 255) nb_s = rloff[255];
    int o0 = rloff[t] - tsum;
    int o1 = o0 + l0, o2 = o1 + l1, o3 = o2 + l2;
    for (int i = t; i < NDEST; i += 256) hist[i] = 0;
    __syncthreads();
    const int nb = min(nb_s, CAP);
    {
        const int2* rp = recs_tmp + (size_t)(b0 + 0) * EPB + s0;
        for (int j = 0; j < l0; ++j) if (o0 + j < CAP) stage[o0 + j] = rp[j];
        rp = recs_tmp + (size_t)(b0 + 1) * EPB + s1;
        for (int j = 0; j < l1; ++j) if (o1 + j < CAP) stage[o1 + j] = rp[j];
        rp = recs_tmp + (size_t)(b0 + 2) * EPB + s2;
        for (int j = 0; j < l2; ++j) if (o2 + j < CAP) stage[o2 + j] = rp[j];
        rp = recs_tmp + (size_t)(b0 + 3) * EPB + s3;
        for (int j = 0; j < l3; ++j) if (o3 + j < CAP) stage[o3 + j] = rp[j];
    }
    __syncthreads();
    for (int j = t; j < nb; j += 256) atomicAdd(&hist[stage[j].x >> 20], 1);
    __syncthreads();
    if (t < NDEST) sc[t] = hist[t];
    __syncthreads();
    for (int off = 1; off < NDEST; off <<= 1) {
        int v = (t >= off && t < NDEST) ? sc[t - off] : 0;
        __syncthreads();
        if (t < NDEST) sc[t] += v;
        __syncthreads();
    }
    if (t < NDEST) {
        int excl = sc[t] - hist[t];
        cursor[t] = excl;
        int gd = (k << DSHIFT) + t;
        if (gd <= nrows) offs[gd] = bb[k] + excl;
    }
    __syncthreads();
    for (int j = t; j < nb; j += 256) {
        int pos = atomicAdd(&cursor[stage[j].x >> 20], 1);
        perm[pos] = j;
    }
    __syncthreads();
    const int base_out = bb[k];
    for (int j = t; j < nb; j += 256) {
        int2 r = stage[perm[j]];
        recs_out[(size_t)base_out + j] = make_int2(r.x & 0xFFFFF, r.y);
    }
}

// ---------------- segment sum: 16 lanes/row, half2 loads, unroll-4 ----------------

__global__ __launch_bounds__(256) void seg_gather16(
    const int* __restrict__ offs, const int2* __restrict__ recs,
    const __half* __restrict__ src16, float* __restrict__ dst, int nrows) {
    const int g = threadIdx.x >> 4, f2 = threadIdx.x & 15;
    const int row = blockIdx.x * 16 + g;
    if (row >= nrows) return;
    int j = offs[row];
    const int j1 = offs[row + 1];
    const __half2* __restrict__ s2 = (const __half2*)src16;
    float ax = 0.0f, ay = 0.0f, bx = 0.0f, by = 0.0f;
    float cx = 0.0f, cy = 0.0f, dx = 0.0f, dy = 0.0f;
    for (; j + 4 <= j1; j += 4) {
        int2 ra = recs[j + 0];
        int2 rb = recs[j + 1];
        int2 rc = recs[j + 2];
        int2 rd = recs[j + 3];
        __half2 ha = s2[(size_t)ra.x * 16 + f2];
        __half2 hb = s2[(size_t)rb.x * 16 + f2];
        __half2 hc = s2[(size_t)rc.x * 16 + f2];
        __half2 hd = s2[(size_t)rd.x * 16 + f2];
        float wa = __int_as_float(ra.y), wb = __int_as_float(rb.y);
        float wc = __int_as_float(rc.y), wd = __int_as_float(rd.y);
        float2 fa = __half22float2(ha), fb = __half22float2(hb);
        float2 fc = __half22float2(hc), fd = __half22float2(hd);
        ax = fmaf(fa.x, wa, ax); ay = fmaf(fa.y, wa, ay);
        bx = fmaf(fb.x, wb, bx); by = fmaf(fb.y, wb, by);
        cx = fmaf(fc.x, wc, cx); cy = fmaf(fc.y, wc, cy);
        dx = fmaf(fd.x, wd, dx); dy = fmaf(fd.y, wd, dy);
    }
    for (; j < j1; ++j) {
        int2 ra = recs[j];
        __half2 ha = s2[(size_t)ra.x * 16 + f2];
        float wa = __int_as_float(ra.y);
        float2 fa = __half22float2(ha);
        ax = fmaf(fa.x, wa, ax); ay = fmaf(fa.y, wa, ay);
    }
    float2 r;
    r.x = (ax + bx) + (cx + dx);
    r.y = (ay + by) + (cy + dy);
    ((float2*)dst)[(size_t)row * 16 + f2] = r;
}

// ---------------- fallback atomic scatter (used only if ws too small) ----------------

__global__ __launch_bounds__(256) void scatter_edges(
    const int* __restrict__ src_idx, const int* __restrict__ dst_idx,
    const float* __restrict__ ev, const float* __restrict__ src,
    float* __restrict__ dst, int n_edges) {
    int e = blockIdx.x * 8 + (threadIdx.x >> 5);
    int f = threadIdx.x & 31;
    if (e >= n_edges) return;
    atomicAdd(&dst[(size_t)dst_idx[e] * FM + f], src[(size_t)src_idx[e] * FM + f] * ev[e]);
}

// ---------------- MLP + LayerNorm kernels ----------------

__global__ __launch_bounds__(256) void pc_mlp(
    const float* __restrict__ cond,
    const float* __restrict__ W1, const float* __restrict__ b1,
    const float* __restrict__ W2, const float* __restrict__ b2,
    float* __restrict__ dst, float* __restrict__ dst2, int nrows) {
    __shared__ float sW2[64 * FM];
    __shared__ float sh[4][64];
    for (int i = threadIdx.x; i < 64 * FM; i += 256) sW2[i] = W2[i];
    int g = threadIdx.x >> 6, l = threadIdx.x & 63, l32 = l & 31, half = l >> 5;
    float w1l = W1[l], b1l = b1[l], b2l = b2[l32];
    __syncthreads();
    for (int row = blockIdx.x * 4 + g; row < nrows; row += gridDim.x * 4) {
        float c = cond[row];
        sh[g][l] = fmaxf(fmaf(c, w1l, b1l), 0.0f);
        float y = 0.0f;
#pragma unroll
        for (int k = 0; k < 32; k += 4) {
            float4 hv = *(const float4*)&sh[g][half * 32 + k];
            y = fmaf(hv.x, sW2[(half * 32 + k + 0) * FM + l32], y);
            y = fmaf(hv.y, sW2[(half * 32 + k + 1) * FM + l32], y);
            y = fmaf(hv.z, sW2[(half * 32 + k + 2) * FM + l32], y);
            y = fmaf(hv.w, sW2[(half * 32 + k + 3) * FM + l32], y);
        }
        y += __shfl_xor(y, 32);
        y += b2l;
        float s = warp_sum32(y);
        float mu = s * (1.0f / 32.0f);
        float d = y - mu;
        float v = warp_sum32(d * d);
        if (half == 0) {
            float o = d * rsqrtf(v * (1.0f / 32.0f) + LN_EPS);
            dst[(size_t)row * FM + l32] = o;
            dst2[(size_t)row * FM + l32] = o;
        }
    }
}

template <int NSEG>
__global__ __launch_bounds__(256) void mlp_ln(
    const float* __restrict__ s0, const float* __restrict__ s1,
    const float* __restrict__ s2,
    const float* __restrict__ W1, const float* __restrict__ b1,
    const float* __restrict__ W2, const float* __restrict__ b2,
    float* __restrict__ dst, __half* __restrict__ dst16, int nrows) {
    constexpr int IN = NSEG * FM;
    __shared__ float sW1[IN * 64];
    __shared__ float sW2[64 * FM];
    __shared__ float sx[4][IN];
    __shared__ float sh[4][64];
    for (int i = threadIdx.x; i < IN * 64; i += 256) sW1[i] = W1[i];
    for (int i = threadIdx.x; i < 64 * FM; i += 256) sW2[i] = W2[i];
    int g = threadIdx.x >> 6, l = threadIdx.x & 63, l32 = l & 31, half = l >> 5;
    float b1l = b1[l], b2l = b2[l32];
    __syncthreads();
    for (int row = blockIdx.x * 4 + g; row < nrows; row += gridDim.x * 4) {
#pragma unroll
        for (int i = l; i < IN; i += 64) {
            const float* s = (i < 32) ? s0 : (i < 64) ? s1 : s2;
            sx[g][i] = s[(size_t)row * FM + (i & 31)];
        }
        float acc = b1l;
#pragma unroll
        for (int k = 0; k < IN; k += 4) {
            float4 xv = *(const float4*)&sx[g][k];
            acc = fmaf(xv.x, sW1[(k + 0) * 64 + l], acc);
            acc = fmaf(xv.y, sW1[(k + 1) * 64 + l], acc);
            acc = fmaf(xv.z, sW1[(k + 2) * 64 + l], acc);
            acc = fmaf(xv.w, sW1[(k + 3) * 64 + l], acc);
        }
        sh[g][l] = fmaxf(acc, 0.0f);
        float y = 0.0f;
#pragma unroll
        for (int k = 0; k < 32; k += 4) {
            float4 hv = *(const float4*)&sh[g][half * 32 + k];
            y = fmaf(hv.x, sW2[(half * 32 + k + 0) * FM + l32], y);
            y = fmaf(hv.y, sW2[(half * 32 + k + 1) * FM + l32], y);
            y = fmaf(hv.z, sW2[(half * 32 + k + 2) * FM + l32], y);
            y = fmaf(hv.w, sW2[(half * 32 + k + 3) * FM + l32], y);
        }
        y += __shfl_xor(y, 32);
        y += b2l;
        float s = warp_sum32(y);
        float mu = s * (1.0f / 32.0f);
        float d = y - mu;
        float v = warp_sum32(d * d);
        if (half == 0) {
            float o = d * rsqrtf(v * (1.0f / 32.0f) + LN_EPS);
            dst[(size_t)row * FM + l32] = o;
            if (dst16) dst16[(size_t)row * FM + l32] = __float2half(o);
        }
    }
}

__global__ __launch_bounds__(256) void out_mlp(
    const float* __restrict__ x,
    const float* __restrict__ W1, const float* __restrict__ b1,
    const float* __restrict__ W2, const float* __restrict__ b2,
    float* __restrict__ dst, int nrows) {
    __shared__ float sW1[FM * 64];
    __shared__ float sW2[64 * 16];
    __shared__ float sx[4][FM];
    __shared__ float sh[4][64];
    for (int i = threadIdx.x; i < FM * 64; i += 256) sW1[i] = W1[i];
    for (int i = threadIdx.x; i < 64 * 16; i += 256) sW2[i] = W2[i];
    int g = threadIdx.x >> 6, l = threadIdx.x & 63;
    int o = l & 15, q = l >> 4;
    float b1l = b1[l];
    float b2o = b2[o];
    __syncthreads();
    for (int row = blockIdx.x * 4 + g; row < nrows; row += gridDim.x * 4) {
        if (l < FM) sx[g][l] = x[(size_t)row * FM + l];
        float acc = b1l;
#pragma unroll
        for (int k = 0; k < FM; k += 4) {
            float4 xv = *(const float4*)&sx[g][k];
            acc = fmaf(xv.x, sW1[(k + 0) * 64 + l], acc);
            acc = fmaf(xv.y, sW1[(k + 1) * 64 + l], acc);
            acc = fmaf(xv.z, sW1[(k + 2) * 64 + l], acc);
            acc = fmaf(xv.w, sW1[(k + 3) * 64 + l], acc);
        }
        sh[g][l] = fmaxf(acc, 0.0f);
        float y = 0.0f;
#pragma unroll
        for (int k = 0; k < 16; k += 4) {
            int kk = q * 16 + k;
            float4 hv = *(const float4*)&sh[g][kk];
            y = fmaf(hv.x, sW2[(kk + 0) * 16 + o], y);
            y = fmaf(hv.y, sW2[(kk + 1) * 16 + o], y);
            y = fmaf(hv.z, sW2[(kk + 2) * 16 + o], y);
            y = fmaf(hv.w, sW2[(kk + 3) * 16 + o], y);
        }
        y += __shfl_xor(y, 16);
        y += __shfl_xor(y, 32);
        if (q == 0) dst[(size_t)row * 16 + o] = 1.0f / (1.0f + expf(-(y + b2o)));
    }
}

// ---------------- launcher ----------------

extern "C" void kernel_launch(void* const* d_in, const int* in_sizes, int n_in,
                              void* d_out, int out_size, void* d_ws, size_t ws_size,
                              hipStream_t stream) {
    const int*   edge_var   = (const int*)d_in[0];
    const int*   edge_const = (const int*)d_in[1];
    const float* edge_val   = (const float*)d_in[2];
    const float* cond       = (const float*)d_in[3];
    const float* pc_W1 = (const float*)d_in[6];
    const float* pc_b1 = (const float*)d_in[7];
    const float* pc_W2 = (const float*)d_in[8];
    const float* pc_b2 = (const float*)d_in[9];
    const float* cu_W1 = (const float*)d_in[10];
    const float* cu_b1 = (const float*)d_in[11];
    const float* cu_W2 = (const float*)d_in[12];
    const float* cu_b2 = (const float*)d_in[13];
    const float* vu_W1 = (const float*)d_in[14];
    const float* vu_b1 = (const float*)d_in[15];
    const float* vu_W2 = (const float*)d_in[16];
    const float* vu_b2 = (const float*)d_in[17];
    const float* out_W1 = (const float*)d_in[18];
    const float* out_b1 = (const float*)d_in[19];
    const float* out_W2 = (const float*)d_in[20];
    const float* out_b2 = (const float*)d_in[21];

    float* ws = (float*)d_ws;
    size_t off = 0;
    auto alloc = [&](size_t nelems) {
        float* p = ws + off;
        off += (nelems + 15) & ~(size_t)15;
        return p;
    };
    float*  emb    = alloc(CONST_COUNT * FM);
    float*  cons   = alloc(CONST_COUNT * FM);
    float*  vars   = alloc(VAR_COUNT * FM);
    float*  msg    = alloc(VAR_COUNT * FM);
    __half* vars16 = (__half*)alloc(VAR_COUNT * FM / 2);
    __half* cons16 = (__half*)alloc(CONST_COUNT * FM / 2);
    int2*   recs_t = (int2*)alloc((size_t)N_EDGES * 2);
    int2*   recs_c = (int2*)alloc((size_t)N_EDGES * 2);
    int2*   recs_v = (int2*)alloc((size_t)N_EDGES * 2);
    int*    lscan  = (int*)alloc((size_t)ABLK * LSTRIDE);
    int*    rlen_T = (int*)alloc((size_t)NB * AB2);
    int*    btot   = (int*)alloc(NB);
    int*    bb_c   = (int*)alloc(NB + 1);
    int*    bb_v   = (int*)alloc(NB + 1);
    int*    offs_c = (int*)alloc(CONST_COUNT + 1);
    int*    offs_v = (int*)alloc(VAR_COUNT + 1);
    size_t need_bytes = off * sizeof(float);
    bool fast = ws_size >= need_bytes;

    if (fast) {
        bucket_sort<6><<<ABLK, 256, 0, stream>>>(edge_const, edge_var, edge_val,
                                                 recs_t, lscan, rlen_T, N_EDGES);
        row_sum<<<NB, 256, 0, stream>>>(rlen_T, btot);
        scan_btot<<<1, 256, 0, stream>>>(btot, bb_c, NB, N_EDGES);
        collect_sort<6, 64><<<NB, 256, 0, stream>>>(recs_t, lscan, rlen_T, bb_c,
                                                    recs_c, offs_c, CONST_COUNT);
        bucket_sort<7><<<ABLK, 256, 0, stream>>>(edge_var, edge_const, edge_val,
                                                 recs_t, lscan, rlen_T, N_EDGES);
        row_sum<<<NB, 256, 0, stream>>>(rlen_T, btot);
        scan_btot<<<1, 256, 0, stream>>>(btot, bb_v, NB, N_EDGES);
        collect_sort<7, 128><<<NB, 256, 0, stream>>>(recs_t, lscan, rlen_T, bb_v,
                                                     recs_v, offs_v, VAR_COUNT);
    }

    init_vars<<<(VAR_COUNT * FM + 255) / 256, 256, 0, stream>>>(
        vars, fast ? vars16 : nullptr, VAR_COUNT * FM);
    pc_mlp<<<1024, 256, 0, stream>>>(cond, pc_W1, pc_b1, pc_W2, pc_b2, emb, cons,
                                     CONST_COUNT);

    for (int pass = 0; pass < 3; ++pass) {
        if (fast) {
            seg_gather16<<<(CONST_COUNT + 15) / 16, 256, 0, stream>>>(
                offs_c, recs_c, vars16, msg, CONST_COUNT);
        } else {
            hipMemsetAsync(msg, 0, (size_t)CONST_COUNT * FM * sizeof(float), stream);
            scatter_edges<<<N_EDGES / 8, 256, 0, stream>>>(edge_var, edge_const, edge_val,
                                                           vars, msg, N_EDGES);
        }
        mlp_ln<3><<<1024, 256, 0, stream>>>(cons, emb, msg, cu_W1, cu_b1, cu_W2, cu_b2,
                                            cons, fast ? cons16 : nullptr, CONST_COUNT);
        if (fast) {
            seg_gather16<<<(VAR_COUNT + 15) / 16, 256, 0, stream>>>(
                offs_v, recs_v, cons16, msg, VAR_COUNT);
        } else {
            hipMemsetAsync(msg, 0, (size_t)VAR_COUNT * FM * sizeof(float), stream);
            scatter_edges<<<N_EDGES / 8, 256, 0, stream>>>(edge_const, edge_var, edge_val,
                                                           cons, msg, N_EDGES);
        }
        mlp_ln<2><<<1024, 256, 0, stream>>>(vars, msg, nullptr, vu_W1, vu_b1, vu_W2, vu_b2,
                                            vars, fast ? vars16 : nullptr, VAR_COUNT);
    }

    out_mlp<<<1024, 256, 0, stream>>>(vars, out_W1, out_b1, out_W2, out_b2,
                                      (float*)d_out, VAR_COUNT);
}

// Round 7
// 664.269 us; speedup vs baseline: 6.8004x; 1.0451x over previous
//
#include <hip/hip_runtime.h>
#include <hip/hip_fp16.h>
#include <math.h>

#define FM 32
#define N_EDGES 3200000
#define VAR_COUNT 100000
#define CONST_COUNT 50000
#define LN_EPS 1e-5f

#define EPB 4096                 // edges per sort block
#define ABLK 782                 // ceil(N_EDGES / EPB)
#define NB 782                   // buckets (64 consts or 128 vars each)
#define AB2 784                  // padded stride for transposed rlen matrix
#define LSTRIDE 784              // NB + 2
#define CAP 4608                 // max records per bucket staged in LDS (+8 sigma)

static __device__ __forceinline__ float warp_sum32(float v) {
#pragma unroll
    for (int m = 16; m; m >>= 1) v += __shfl_xor(v, m);
    return v;
}

__global__ void init_vars(float* __restrict__ v, __half* __restrict__ v16, int n) {
    int i = blockIdx.x * 256 + threadIdx.x;
    if (i < n) { v[i] = 1.0f; if (v16) v16[i] = __float2half(1.0f); }
}

// ---------------- block-local bucket sort (no global atomics) ----------------

template <int DSHIFT>
__global__ __launch_bounds__(256) void bucket_sort(
    const int* __restrict__ dest_arr, const int* __restrict__ src_arr,
    const float* __restrict__ val_arr,
    int2* __restrict__ recs_tmp, int* __restrict__ lscan, int* __restrict__ rlen_T,
    int n) {
    __shared__ int hist[NB];
    __shared__ int cursor[NB];
    __shared__ int chunk[256];
    __shared__ int2 stage[EPB];
    const int t = threadIdx.x;
    const int base = blockIdx.x * EPB;
    const int nb = min(EPB, n - base);
    for (int i = t; i < NB; i += 256) hist[i] = 0;
    __syncthreads();
    int dg[16], pk[16], vb[16];
#pragma unroll
    for (int k = 0; k < 16; ++k) {
        int j = k * 256 + t;
        dg[k] = -1;
        if (j < nb) {
            int dest = dest_arr[base + j];
            int src  = src_arr[base + j];
            vb[k] = __float_as_int(val_arr[base + j]);
            dg[k] = dest >> DSHIFT;
            pk[k] = ((dest & ((1 << DSHIFT) - 1)) << 20) | src;
            atomicAdd(&hist[dg[k]], 1);
        }
    }
    __syncthreads();
    int sum = 0;
#pragma unroll
    for (int k = 0; k < 4; ++k) {
        int idx = t * 4 + k;
        if (idx < NB) sum += hist[idx];
    }
    chunk[t] = sum;
    __syncthreads();
    for (int off = 1; off < 256; off <<= 1) {
        int v = (t >= off) ? chunk[t - off] : 0;
        __syncthreads();
        chunk[t] += v;
        __syncthreads();
    }
    int run = chunk[t] - sum;
#pragma unroll
    for (int k = 0; k < 4; ++k) {
        int idx = t * 4 + k;
        if (idx < NB) {
            int h = hist[idx];
            rlen_T[(size_t)idx * AB2 + blockIdx.x] = h;
            hist[idx] = run;
            cursor[idx] = run;
            run += h;
        }
    }
    __syncthreads();
    {
        int* lp = lscan + (size_t)blockIdx.x * LSTRIDE;
        for (int i = t; i < NB; i += 256) lp[i] = hist[i];
        if (t == 0) lp[NB] = nb;
    }
#pragma unroll
    for (int k = 0; k < 16; ++k) {
        if (dg[k] >= 0) {
            int pos = atomicAdd(&cursor[dg[k]], 1);
            stage[pos] = make_int2(pk[k], vb[k]);
        }
    }
    __syncthreads();
    for (int j = t; j < nb; j += 256) recs_tmp[(size_t)base + j] = stage[j];
}

// Bucket totals: btot[k] = sum_b rlen_T[k][b] (coalesced row sum).
__global__ __launch_bounds__(256) void row_sum(const int* __restrict__ rlen_T,
                                               int* __restrict__ btot) {
    __shared__ int ls[256];
    const int t = threadIdx.x;
    const int* rp = rlen_T + (size_t)blockIdx.x * AB2;
    int s = 0;
    for (int b = t; b < ABLK; b += 256) s += rp[b];
    ls[t] = s;
    __syncthreads();
    for (int off = 128; off; off >>= 1) {
        if (t < off) ls[t] += ls[t + off];
        __syncthreads();
    }
    if (t == 0) btot[blockIdx.x] = ls[0];
}

// Exclusive scan of bucket totals -> bucket base offsets bb[0..NB], bb[NB]=total.
__global__ __launch_bounds__(256) void scan_btot(
    const int* __restrict__ btot, int* __restrict__ bb, int n, int total) {
    __shared__ int ls[256];
    const int t = threadIdx.x;
    int idx = t * 4;
    int a0 = (idx + 0 < n) ? btot[idx + 0] : 0;
    int a1 = (idx + 1 < n) ? btot[idx + 1] : 0;
    int a2 = (idx + 2 < n) ? btot[idx + 2] : 0;
    int a3 = (idx + 3 < n) ? btot[idx + 3] : 0;
    int tsum = a0 + a1 + a2 + a3;
    ls[t] = tsum;
    __syncthreads();
    for (int off = 1; off < 256; off <<= 1) {
        int v = (t >= off) ? ls[t - off] : 0;
        __syncthreads();
        ls[t] += v;
        __syncthreads();
    }
    int excl = ls[t] - tsum;
    if (idx + 0 < n) bb[idx + 0] = excl;
    if (idx + 1 < n) bb[idx + 1] = excl + a0;
    if (idx + 2 < n) bb[idx + 2] = excl + a0 + a1;
    if (idx + 3 < n) bb[idx + 3] = excl + a0 + a1 + a2;
    if (t == 0) bb[n] = total;
}

// ---------------- collect + final counting sort per bucket ----------------
// Direct-to-global scatter in the rank phase (36 KB L2-resident window per
// block); also accumulates per-dest weight sums (wsum) for the pass-0 shortcut.

template <int DSHIFT, int NDEST>
__global__ __launch_bounds__(256) void collect_sort(
    const int2* __restrict__ recs_tmp, const int* __restrict__ lscan,
    const int* __restrict__ rlen_T, const int* __restrict__ bb,
    int2* __restrict__ recs_out, int* __restrict__ offs,
    float* __restrict__ wsum, int nrows) {
    __shared__ int2 stage[CAP];
    __shared__ int rloff[256];
    __shared__ int hist[NDEST];
    __shared__ int cursor[NDEST];
    __shared__ int sc[NDEST];
    __shared__ float wsumL[NDEST];
    __shared__ int nb_s;
    const int t = threadIdx.x;
    const int k = blockIdx.x;
    const int b0 = t * 4;
    int s0 = 0, s1 = 0, s2 = 0, s3 = 0, l0 = 0, l1 = 0, l2 = 0, l3 = 0;
    if (b0 + 0 < ABLK) { s0 = lscan[(size_t)(b0 + 0) * LSTRIDE + k]; l0 = rlen_T[(size_t)k * AB2 + b0 + 0]; }
    if (b0 + 1 < ABLK) { s1 = lscan[(size_t)(b0 + 1) * LSTRIDE + k]; l1 = rlen_T[(size_t)k * AB2 + b0 + 1]; }
    if (b0 + 2 < ABLK) { s2 = lscan[(size_t)(b0 + 2) * LSTRIDE + k]; l2 = rlen_T[(size_t)k * AB2 + b0 + 2]; }
    if (b0 + 3 < ABLK) { s3 = lscan[(size_t)(b0 + 3) * LSTRIDE + k]; l3 = rlen_T[(size_t)k * AB2 + b0 + 3]; }
    int tsum = l0 + l1 + l2 + l3;
    rloff[t] = tsum;
    __syncthreads();
    for (int off = 1; off < 256; off <<= 1) {
        int v = (t >= off) ? rloff[t - off] : 0;
        __syncthreads();
        rloff[t] += v;
        __syncthreads();
    }
    if (t == 255) nb_s = rloff[255];
    int o0 = rloff[t] - tsum;
    int o1 = o0 + l0, o2 = o1 + l1, o3 = o2 + l2;
    for (int i = t; i < NDEST; i += 256) { hist[i] = 0; wsumL[i] = 0.0f; }
    __syncthreads();
    const int nb = min(nb_s, CAP);
    {
        const int2* rp = recs_tmp + (size_t)(b0 + 0) * EPB + s0;
        for (int j = 0; j < l0; ++j) if (o0 + j < CAP) stage[o0 + j] = rp[j];
        rp = recs_tmp + (size_t)(b0 + 1) * EPB + s1;
        for (int j = 0; j < l1; ++j) if (o1 + j < CAP) stage[o1 + j] = rp[j];
        rp = recs_tmp + (size_t)(b0 + 2) * EPB + s2;
        for (int j = 0; j < l2; ++j) if (o2 + j < CAP) stage[o2 + j] = rp[j];
        rp = recs_tmp + (size_t)(b0 + 3) * EPB + s3;
        for (int j = 0; j < l3; ++j) if (o3 + j < CAP) stage[o3 + j] = rp[j];
    }
    __syncthreads();
    for (int j = t; j < nb; j += 256) {
        int2 r = stage[j];
        atomicAdd(&hist[r.x >> 20], 1);
        if (wsum) atomicAdd(&wsumL[r.x >> 20], __int_as_float(r.y));
    }
    __syncthreads();
    if (t < NDEST) sc[t] = hist[t];
    __syncthreads();
    for (int off = 1; off < NDEST; off <<= 1) {
        int v = (t >= off && t < NDEST) ? sc[t - off] : 0;
        __syncthreads();
        if (t < NDEST) sc[t] += v;
        __syncthreads();
    }
    if (t < NDEST) {
        int excl = sc[t] - hist[t];
        cursor[t] = excl;
        int gd = (k << DSHIFT) + t;
        if (gd <= nrows) offs[gd] = bb[k] + excl;
        if (wsum && gd < nrows) wsum[gd] = wsumL[t];
    }
    __syncthreads();
    // rank + direct global scatter (order within dest arbitrary)
    const int base_out = bb[k];
    for (int j = t; j < nb; j += 256) {
        int2 r = stage[j];
        int pos = atomicAdd(&cursor[r.x >> 20], 1);
        recs_out[(size_t)base_out + pos] = make_int2(r.x & 0xFFFFF, r.y);
    }
}

// ---------------- segment sum: 16 lanes/row, half2 loads, unroll-8 ----------------

__global__ __launch_bounds__(256) void seg_gather16(
    const int* __restrict__ offs, const int2* __restrict__ recs,
    const __half* __restrict__ src16, float* __restrict__ dst, int nrows) {
    const int g = threadIdx.x >> 4, f2 = threadIdx.x & 15;
    const int row = blockIdx.x * 16 + g;
    if (row >= nrows) return;
    int j = offs[row];
    const int j1 = offs[row + 1];
    const __half2* __restrict__ s2 = (const __half2*)src16;
    float ax[8], ay[8];
#pragma unroll
    for (int u = 0; u < 8; ++u) { ax[u] = 0.0f; ay[u] = 0.0f; }
    for (; j + 8 <= j1; j += 8) {
        int2 r[8];
#pragma unroll
        for (int u = 0; u < 8; ++u) r[u] = recs[j + u];
        __half2 h[8];
#pragma unroll
        for (int u = 0; u < 8; ++u) h[u] = s2[(size_t)r[u].x * 16 + f2];
#pragma unroll
        for (int u = 0; u < 8; ++u) {
            float w = __int_as_float(r[u].y);
            float2 f = __half22float2(h[u]);
            ax[u] = fmaf(f.x, w, ax[u]);
            ay[u] = fmaf(f.y, w, ay[u]);
        }
    }
    for (; j < j1; ++j) {
        int2 ra = recs[j];
        __half2 ha = s2[(size_t)ra.x * 16 + f2];
        float wa = __int_as_float(ra.y);
        float2 fa = __half22float2(ha);
        ax[0] = fmaf(fa.x, wa, ax[0]);
        ay[0] = fmaf(fa.y, wa, ay[0]);
    }
    float2 r;
    r.x = ((ax[0] + ax[1]) + (ax[2] + ax[3])) + ((ax[4] + ax[5]) + (ax[6] + ax[7]));
    r.y = ((ay[0] + ay[1]) + (ay[2] + ay[3])) + ((ay[4] + ay[5]) + (ay[6] + ay[7]));
    ((float2*)dst)[(size_t)row * 16 + f2] = r;
}

// ---------------- fallback atomic scatter (used only if ws too small) ----------------

__global__ __launch_bounds__(256) void scatter_edges(
    const int* __restrict__ src_idx, const int* __restrict__ dst_idx,
    const float* __restrict__ ev, const float* __restrict__ src,
    float* __restrict__ dst, int n_edges) {
    int e = blockIdx.x * 8 + (threadIdx.x >> 5);
    int f = threadIdx.x & 31;
    if (e >= n_edges) return;
    atomicAdd(&dst[(size_t)dst_idx[e] * FM + f], src[(size_t)src_idx[e] * FM + f] * ev[e]);
}

// ---------------- MLP + LayerNorm kernels ----------------

__global__ __launch_bounds__(256) void pc_mlp(
    const float* __restrict__ cond,
    const float* __restrict__ W1, const float* __restrict__ b1,
    const float* __restrict__ W2, const float* __restrict__ b2,
    float* __restrict__ dst, float* __restrict__ dst2, int nrows) {
    __shared__ float sW2[64 * FM];
    __shared__ float sh[4][64];
    for (int i = threadIdx.x; i < 64 * FM; i += 256) sW2[i] = W2[i];
    int g = threadIdx.x >> 6, l = threadIdx.x & 63, l32 = l & 31, half = l >> 5;
    float w1l = W1[l], b1l = b1[l], b2l = b2[l32];
    __syncthreads();
    for (int row = blockIdx.x * 4 + g; row < nrows; row += gridDim.x * 4) {
        float c = cond[row];
        sh[g][l] = fmaxf(fmaf(c, w1l, b1l), 0.0f);
        float y = 0.0f;
#pragma unroll
        for (int k = 0; k < 32; k += 4) {
            float4 hv = *(const float4*)&sh[g][half * 32 + k];
            y = fmaf(hv.x, sW2[(half * 32 + k + 0) * FM + l32], y);
            y = fmaf(hv.y, sW2[(half * 32 + k + 1) * FM + l32], y);
            y = fmaf(hv.z, sW2[(half * 32 + k + 2) * FM + l32], y);
            y = fmaf(hv.w, sW2[(half * 32 + k + 3) * FM + l32], y);
        }
        y += __shfl_xor(y, 32);
        y += b2l;
        float s = warp_sum32(y);
        float mu = s * (1.0f / 32.0f);
        float d = y - mu;
        float v = warp_sum32(d * d);
        if (half == 0) {
            float o = d * rsqrtf(v * (1.0f / 32.0f) + LN_EPS);
            dst[(size_t)row * FM + l32] = o;
            dst2[(size_t)row * FM + l32] = o;
        }
    }
}

// IN = NSEG*32 -> 64 (relu) -> 32, LN. Layer-1 weights in registers (per-lane
// column W1[:,l]). If ws != nullptr (NSEG==3), the third input segment is the
// broadcast scalar ws[row] (pass-0 v2c shortcut).
template <int NSEG>
__global__ __launch_bounds__(256) void mlp_ln(
    const float* __restrict__ s0, const float* __restrict__ s1,
    const float* __restrict__ s2, const float* __restrict__ ws,
    const float* __restrict__ W1, const float* __restrict__ b1,
    const float* __restrict__ W2, const float* __restrict__ b2,
    float* __restrict__ dst, __half* __restrict__ dst16, int nrows) {
    constexpr int IN = NSEG * FM;
    __shared__ float sW2[64 * FM];
    __shared__ float sx[4][IN];
    __shared__ float sh[4][64];
    for (int i = threadIdx.x; i < 64 * FM; i += 256) sW2[i] = W2[i];
    int g = threadIdx.x >> 6, l = threadIdx.x & 63, l32 = l & 31, half = l >> 5;
    float w1r[IN];
#pragma unroll
    for (int k = 0; k < IN; ++k) w1r[k] = W1[k * 64 + l];
    float b1l = b1[l], b2l = b2[l32];
    __syncthreads();
    for (int row = blockIdx.x * 4 + g; row < nrows; row += gridDim.x * 4) {
#pragma unroll
        for (int i = l; i < IN; i += 64) {
            float v;
            if (NSEG >= 3 && i >= 64)
                v = ws ? ws[row] : s2[(size_t)row * FM + (i & 31)];
            else
                v = (i < 32 ? s0 : s1)[(size_t)row * FM + (i & 31)];
            sx[g][i] = v;
        }
        float acc = b1l;
#pragma unroll
        for (int k = 0; k < IN; k += 4) {
            float4 xv = *(const float4*)&sx[g][k];
            acc = fmaf(xv.x, w1r[k + 0], acc);
            acc = fmaf(xv.y, w1r[k + 1], acc);
            acc = fmaf(xv.z, w1r[k + 2], acc);
            acc = fmaf(xv.w, w1r[k + 3], acc);
        }
        sh[g][l] = fmaxf(acc, 0.0f);
        float y = 0.0f;
#pragma unroll
        for (int k = 0; k < 32; k += 4) {
            float4 hv = *(const float4*)&sh[g][half * 32 + k];
            y = fmaf(hv.x, sW2[(half * 32 + k + 0) * FM + l32], y);
            y = fmaf(hv.y, sW2[(half * 32 + k + 1) * FM + l32], y);
            y = fmaf(hv.z, sW2[(half * 32 + k + 2) * FM + l32], y);
            y = fmaf(hv.w, sW2[(half * 32 + k + 3) * FM + l32], y);
        }
        y += __shfl_xor(y, 32);
        y += b2l;
        float s = warp_sum32(y);
        float mu = s * (1.0f / 32.0f);
        float d = y - mu;
        float v = warp_sum32(d * d);
        if (half == 0) {
            float o = d * rsqrtf(v * (1.0f / 32.0f) + LN_EPS);
            dst[(size_t)row * FM + l32] = o;
            if (dst16) dst16[(size_t)row * FM + l32] = __float2half(o);
        }
    }
}

__global__ __launch_bounds__(256) void out_mlp(
    const float* __restrict__ x,
    const float* __restrict__ W1, const float* __restrict__ b1,
    const float* __restrict__ W2, const float* __restrict__ b2,
    float* __restrict__ dst, int nrows) {
    __shared__ float sW2[64 * 16];
    __shared__ float sx[4][FM];
    __shared__ float sh[4][64];
    for (int i = threadIdx.x; i < 64 * 16; i += 256) sW2[i] = W2[i];
    int g = threadIdx.x >> 6, l = threadIdx.x & 63;
    int o = l & 15, q = l >> 4;
    float w1r[FM];
#pragma unroll
    for (int k = 0; k < FM; ++k) w1r[k] = W1[k * 64 + l];
    float b1l = b1[l];
    float b2o = b2[o];
    __syncthreads();
    for (int row = blockIdx.x * 4 + g; row < nrows; row += gridDim.x * 4) {
        if (l < FM) sx[g][l] = x[(size_t)row * FM + l];
        float acc = b1l;
#pragma unroll
        for (int k = 0; k < FM; k += 4) {
            float4 xv = *(const float4*)&sx[g][k];
            acc = fmaf(xv.x, w1r[k + 0], acc);
            acc = fmaf(xv.y, w1r[k + 1], acc);
            acc = fmaf(xv.z, w1r[k + 2], acc);
            acc = fmaf(xv.w, w1r[k + 3], acc);
        }
        sh[g][l] = fmaxf(acc, 0.0f);
        float y = 0.0f;
#pragma unroll
        for (int k = 0; k < 16; k += 4) {
            int kk = q * 16 + k;
            float4 hv = *(const float4*)&sh[g][kk];
            y = fmaf(hv.x, sW2[(kk + 0) * 16 + o], y);
            y = fmaf(hv.y, sW2[(kk + 1) * 16 + o], y);
            y = fmaf(hv.z, sW2[(kk + 2) * 16 + o], y);
            y = fmaf(hv.w, sW2[(kk + 3) * 16 + o], y);
        }
        y += __shfl_xor(y, 16);
        y += __shfl_xor(y, 32);
        if (q == 0) dst[(size_t)row * 16 + o] = 1.0f / (1.0f + expf(-(y + b2o)));
    }
}

// ---------------- launcher ----------------

extern "C" void kernel_launch(void* const* d_in, const int* in_sizes, int n_in,
                              void* d_out, int out_size, void* d_ws, size_t ws_size,
                              hipStream_t stream) {
    const int*   edge_var   = (const int*)d_in[0];
    const int*   edge_const = (const int*)d_in[1];
    const float* edge_val   = (const float*)d_in[2];
    const float* cond       = (const float*)d_in[3];
    const float* pc_W1 = (const float*)d_in[6];
    const float* pc_b1 = (const float*)d_in[7];
    const float* pc_W2 = (const float*)d_in[8];
    const float* pc_b2 = (const float*)d_in[9];
    const float* cu_W1 = (const float*)d_in[10];
    const float* cu_b1 = (const float*)d_in[11];
    const float* cu_W2 = (const float*)d_in[12];
    const float* cu_b2 = (const float*)d_in[13];
    const float* vu_W1 = (const float*)d_in[14];
    const float* vu_b1 = (const float*)d_in[15];
    const float* vu_W2 = (const float*)d_in[16];
    const float* vu_b2 = (const float*)d_in[17];
    const float* out_W1 = (const float*)d_in[18];
    const float* out_b1 = (const float*)d_in[19];
    const float* out_W2 = (const float*)d_in[20];
    const float* out_b2 = (const float*)d_in[21];

    float* ws = (float*)d_ws;
    size_t off = 0;
    auto alloc = [&](size_t nelems) {
        float* p = ws + off;
        off += (nelems + 15) & ~(size_t)15;
        return p;
    };
    float*  emb    = alloc(CONST_COUNT * FM);
    float*  cons   = alloc(CONST_COUNT * FM);
    float*  vars   = alloc(VAR_COUNT * FM);
    float*  msg    = alloc(VAR_COUNT * FM);
    __half* vars16 = (__half*)alloc(VAR_COUNT * FM / 2);
    __half* cons16 = (__half*)alloc(CONST_COUNT * FM / 2);
    int2*   recs_t = (int2*)alloc((size_t)N_EDGES * 2);
    int2*   recs_c = (int2*)alloc((size_t)N_EDGES * 2);
    int2*   recs_v = (int2*)alloc((size_t)N_EDGES * 2);
    int*    lscan  = (int*)alloc((size_t)ABLK * LSTRIDE);
    int*    rlen_T = (int*)alloc((size_t)NB * AB2);
    int*    btot   = (int*)alloc(NB);
    int*    bb_c   = (int*)alloc(NB + 1);
    int*    bb_v   = (int*)alloc(NB + 1);
    int*    offs_c = (int*)alloc(CONST_COUNT + 1);
    int*    offs_v = (int*)alloc(VAR_COUNT + 1);
    float*  wsum_c = alloc(CONST_COUNT);
    size_t need_bytes = off * sizeof(float);
    bool fast = ws_size >= need_bytes;

    if (fast) {
        bucket_sort<6><<<ABLK, 256, 0, stream>>>(edge_const, edge_var, edge_val,
                                                 recs_t, lscan, rlen_T, N_EDGES);
        row_sum<<<NB, 256, 0, stream>>>(rlen_T, btot);
        scan_btot<<<1, 256, 0, stream>>>(btot, bb_c, NB, N_EDGES);
        collect_sort<6, 64><<<NB, 256, 0, stream>>>(recs_t, lscan, rlen_T, bb_c,
                                                    recs_c, offs_c, wsum_c, CONST_COUNT);
        bucket_sort<7><<<ABLK, 256, 0, stream>>>(edge_var, edge_const, edge_val,
                                                 recs_t, lscan, rlen_T, N_EDGES);
        row_sum<<<NB, 256, 0, stream>>>(rlen_T, btot);
        scan_btot<<<1, 256, 0, stream>>>(btot, bb_v, NB, N_EDGES);
        collect_sort<7, 128><<<NB, 256, 0, stream>>>(recs_t, lscan, rlen_T, bb_v,
                                                     recs_v, offs_v, nullptr, VAR_COUNT);
    }

    init_vars<<<(VAR_COUNT * FM + 255) / 256, 256, 0, stream>>>(
        vars, fast ? vars16 : nullptr, VAR_COUNT * FM);
    pc_mlp<<<1024, 256, 0, stream>>>(cond, pc_W1, pc_b1, pc_W2, pc_b2, emb, cons,
                                     CONST_COUNT);

    for (int pass = 0; pass < 3; ++pass) {
        if (fast) {
            if (pass == 0) {
                // v2c pass 0: variables == ones -> broadcast wsum_c (no gather)
                mlp_ln<3><<<1024, 256, 0, stream>>>(cons, emb, nullptr, wsum_c,
                                                    cu_W1, cu_b1, cu_W2, cu_b2,
                                                    cons, cons16, CONST_COUNT);
            } else {
                seg_gather16<<<(CONST_COUNT + 15) / 16, 256, 0, stream>>>(
                    offs_c, recs_c, vars16, msg, CONST_COUNT);
                mlp_ln<3><<<1024, 256, 0, stream>>>(cons, emb, msg, nullptr,
                                                    cu_W1, cu_b1, cu_W2, cu_b2,
                                                    cons, cons16, CONST_COUNT);
            }
        } else {
            hipMemsetAsync(msg, 0, (size_t)CONST_COUNT * FM * sizeof(float), stream);
            scatter_edges<<<N_EDGES / 8, 256, 0, stream>>>(edge_var, edge_const, edge_val,
                                                           vars, msg, N_EDGES);
            mlp_ln<3><<<1024, 256, 0, stream>>>(cons, emb, msg, nullptr,
                                                cu_W1, cu_b1, cu_W2, cu_b2,
                                                cons, nullptr, CONST_COUNT);
        }
        if (fast) {
            seg_gather16<<<(VAR_COUNT + 15) / 16, 256, 0, stream>>>(
                offs_v, recs_v, cons16, msg, VAR_COUNT);
        } else {
            hipMemsetAsync(msg, 0, (size_t)VAR_COUNT * FM * sizeof(float), stream);
            scatter_edges<<<N_EDGES / 8, 256, 0, stream>>>(edge_const, edge_var, edge_val,
                                                           cons, msg, N_EDGES);
        }
        mlp_ln<2><<<1024, 256, 0, stream>>>(vars, msg, nullptr, nullptr,
                                            vu_W1, vu_b1, vu_W2, vu_b2,
                                            vars, fast ? vars16 : nullptr, VAR_COUNT);
    }

    out_mlp<<<1024, 256, 0, stream>>>(vars, out_W1, out_b1, out_W2, out_b2,
                                      (float*)d_out, VAR_COUNT);
}